// Round 13
// baseline (179.360 us; speedup 1.0000x reference)
//
#include <hip/hip_runtime.h>
#include <hip/hip_bf16.h>
#include <cstdint>

#define BQ 8
#define NQ 2048
#define FQ 128
#define NG (NQ * 16)            // adjF n-group stride (elems)

typedef __attribute__((ext_vector_type(8))) short short8;
typedef __attribute__((ext_vector_type(4))) float f32x4;
typedef __attribute__((ext_vector_type(8))) unsigned short us8;
typedef __attribute__((ext_vector_type(2))) unsigned int u32x2;

__device__ __forceinline__ unsigned short f2bf(float f) {
    union { float f; unsigned int u; } c; c.f = f;
    unsigned int u = c.u;
    u = (u + 0x7FFFu + ((u >> 16) & 1u)) >> 16;   // RNE
    return (unsigned short)u;
}
__device__ __forceinline__ float bf2f(unsigned short u) {
    union { unsigned int i; float f; } c; c.i = (unsigned int)u << 16; return c.f;
}
__device__ __forceinline__ unsigned int cvtpk(float lo, float hi) {
    unsigned int r;
    asm("v_cvt_pk_bf16_f32 %0, %1, %2" : "=v"(r) : "v"(lo), "v"(hi));
    return r;
}

// Fragment layouts (per batch):
//   xnF : [n/16][k/8][n%16][k%8]   addr = (n>>4)*2048 + (k>>3)*128 + (n&15)*8 + (k&7)
//   adjF: [n/16][m/8][n%16][m%8]   addr = (n>>4)*NG   + (m>>3)*128 + (n&15)*8 + (m&7)
//   hsF : [m/8][f][m%8]            addr = (m>>3)*1024 + f*8 + (m&7)
// hpart, h are bf16 row-major [n][f].
// r13: adjF + hpart are write-once/read-once streams -> nontemporal (skip L2
// retention; reads served from L3). hsF/xnF stay cached (reused).

// ---- Kernel 1a: row L2-normalize x -> xnF (16 rows/block) ----
__global__ __launch_bounds__(256) void k_rownorm(const float* __restrict__ h,
                                                 unsigned short* __restrict__ xnF) {
    int t = threadIdx.x;
    int rl = t >> 4, j = t & 15;
    size_t row = (size_t)blockIdx.x * 16 + rl;
    const float* hr = h + row * FQ + j * 8;
    float v[8];
    #pragma unroll
    for (int e = 0; e < 8; ++e) v[e] = hr[e];
    float s = 0.f;
    #pragma unroll
    for (int e = 0; e < 8; ++e) s += v[e] * v[e];
    s += __shfl_xor(s, 1, 64);
    s += __shfl_xor(s, 2, 64);
    s += __shfl_xor(s, 4, 64);
    s += __shfl_xor(s, 8, 64);
    float inv = 1.0f / fmaxf(sqrtf(s), 1e-8f);
    us8 u;
    #pragma unroll
    for (int e = 0; e < 8; ++e) u[e] = f2bf(v[e] * inv);
    *(us8*)(xnF + (size_t)blockIdx.x * 2048 + j * 128 + rl * 8) = u;
}

// ---- Kernel 1b: reduce bf16 K-split partials -> bf16 h, normalize -> xnF ----
template<int KC>
__global__ __launch_bounds__(256) void k_rownorm4(const unsigned short* __restrict__ hp,
                                                  unsigned short* __restrict__ hout,
                                                  unsigned short* __restrict__ xnF) {
    const size_t CS = (size_t)BQ * NQ * FQ;
    int t = threadIdx.x;
    int rl = t >> 4, j = t & 15;
    size_t row = (size_t)blockIdx.x * 16 + rl;
    size_t o = row * FQ + j * 8;
    float v[8] = {0.f, 0.f, 0.f, 0.f, 0.f, 0.f, 0.f, 0.f};
    #pragma unroll
    for (int k = 0; k < KC; ++k) {
        us8 pv = __builtin_nontemporal_load((const us8*)(hp + k * CS + o));
        #pragma unroll
        for (int e = 0; e < 8; ++e) v[e] += bf2f(pv[e]);
    }
    us8 hw;
    #pragma unroll
    for (int e = 0; e < 8; ++e) hw[e] = f2bf(v[e]);
    *(us8*)(hout + o) = hw;
    float s = 0.f;
    #pragma unroll
    for (int e = 0; e < 8; ++e) s += v[e] * v[e];
    s += __shfl_xor(s, 1, 64);
    s += __shfl_xor(s, 2, 64);
    s += __shfl_xor(s, 4, 64);
    s += __shfl_xor(s, 8, 64);
    float inv = 1.0f / fmaxf(sqrtf(s), 1e-8f);
    us8 u;
    #pragma unroll
    for (int e = 0; e < 8; ++e) u[e] = f2bf(v[e] * inv);
    *(us8*)(xnF + (size_t)blockIdx.x * 2048 + j * 128 + rl * 8) = u;
}

// ---- Kernel 2: S = xn@xn^T, threshold, transposed NT store to adjF, dpart sums.
//      128x128 tile per 512-thr block; 8 waves = 4 row-quarters x 2 col-halves. ----
__global__ __launch_bounds__(512) void k_adj(const unsigned short* __restrict__ xnF,
                                             unsigned short* __restrict__ adjF,
                                             float* __restrict__ dpart, float t) {
    int bid = blockIdx.x;
    int blk = (bid & 7) * (int)(gridDim.x >> 3) + (bid >> 3);   // XCD swizzle
    int bb  = blk >> 8;
    int ij  = blk & 255;
    int I   = ij >> 4, J = ij & 15;
    int wid = threadIdx.x >> 6, lane = threadIdx.x & 63;
    int wr = wid >> 1, wc = wid & 1;
    int g = lane >> 4, c = lane & 15;

    const unsigned short* xb = xnF + (size_t)bb * NQ * FQ;
    int rowb = I * 128 + wr * 32;
    int colb = J * 128 + wc * 64;

    short8 a[2][4];
    #pragma unroll
    for (int mi = 0; mi < 2; ++mi)
        #pragma unroll
        for (int ks = 0; ks < 4; ++ks)
            a[mi][ks] = *(const short8*)(xb + (size_t)((rowb >> 4) + mi) * 2048 + (ks * 4 + g) * 128 + c * 8);

    f32x4 acc[2][4];
    #pragma unroll
    for (int mi = 0; mi < 2; ++mi)
        #pragma unroll
        for (int ni = 0; ni < 4; ++ni) acc[mi][ni] = (f32x4){0.f, 0.f, 0.f, 0.f};

    #pragma unroll
    for (int ni = 0; ni < 4; ++ni) {
        short8 b[4];
        #pragma unroll
        for (int ks = 0; ks < 4; ++ks)
            b[ks] = *(const short8*)(xb + (size_t)((colb >> 4) + ni) * 2048 + (ks * 4 + g) * 128 + c * 8);
        #pragma unroll
        for (int mi = 0; mi < 2; ++mi)
            #pragma unroll
            for (int ks = 0; ks < 4; ++ks)
                acc[mi][ni] = __builtin_amdgcn_mfma_f32_16x16x32_bf16(a[mi][ks], b[ks], acc[mi][ni], 0, 0, 0);
    }

    unsigned short* adjb = adjF + (size_t)bb * NQ * NQ;
    __shared__ float dsm[2][128];
    float dl[2][4];
    #pragma unroll
    for (int mi = 0; mi < 2; ++mi)
        #pragma unroll
        for (int r = 0; r < 4; ++r) dl[mi][r] = 0.f;

    #pragma unroll
    for (int mi = 0; mi < 2; ++mi)
        #pragma unroll
        for (int ni = 0; ni < 4; ++ni) {
            f32x4 v = acc[mi][ni];
            float x0 = (v[0] > t) ? v[0] : 0.0f;   // strict threshold in f32
            float x1 = (v[1] > t) ? v[1] : 0.0f;
            float x2 = (v[2] > t) ? v[2] : 0.0f;
            float x3 = (v[3] > t) ? v[3] : 0.0f;
            dl[mi][0] += x0; dl[mi][1] += x1; dl[mi][2] += x2; dl[mi][3] += x3;
            u32x2 u;
            u[0] = cvtpk(x0, x1);
            u[1] = cvtpk(x2, x3);
            __builtin_nontemporal_store(u,
                (u32x2*)(adjb + (size_t)((colb >> 4) + ni) * NG
                              + (size_t)((rowb >> 3) + mi * 2 + (g >> 1)) * 128
                              + c * 8 + (g & 1) * 4));
        }

    #pragma unroll
    for (int mi = 0; mi < 2; ++mi)
        #pragma unroll
        for (int r = 0; r < 4; ++r) {
            float s = dl[mi][r];
            s += __shfl_xor(s, 1, 64);
            s += __shfl_xor(s, 2, 64);
            s += __shfl_xor(s, 4, 64);
            s += __shfl_xor(s, 8, 64);
            dl[mi][r] = s;
        }
    if (c == 0) {
        #pragma unroll
        for (int mi = 0; mi < 2; ++mi)
            #pragma unroll
            for (int r = 0; r < 4; ++r)
                dsm[wc][wr * 32 + mi * 16 + g * 4 + r] = dl[mi][r];
    }
    __syncthreads();
    int tid = threadIdx.x;
    if (tid < 128)
        dpart[((size_t)J * 8 + bb) * NQ + I * 128 + tid] = dsm[0][tid] + dsm[1][tid];
}

// ---- Kernel 3a (iter 0): isq from dpart; hsF from f32 x ----
__global__ __launch_bounds__(256) void k_prep_f32(const float* __restrict__ h,
                                                  const float* __restrict__ dpart,
                                                  float* __restrict__ isq,
                                                  unsigned short* __restrict__ hsF) {
    __shared__ float tile[32][129];
    __shared__ float iv[32];
    int r0 = blockIdx.x * 32;
    int bb = r0 >> 11;
    int m0 = r0 & (NQ - 1);
    int tid = threadIdx.x;
    if (tid < 32) {
        float s = 0.f;
        #pragma unroll
        for (int j = 0; j < 16; ++j)
            s += dpart[((size_t)j * 8 + bb) * NQ + m0 + tid];
        float v = 1.0f / sqrtf(s);
        iv[tid] = v;
        isq[r0 + tid] = v;
    }
    #pragma unroll
    for (int it = 0; it < 16; ++it) {
        int idx = tid + it * 256;
        int mi = idx >> 7, f = idx & 127;
        tile[mi][f] = h[(size_t)(r0 + mi) * FQ + f];
    }
    __syncthreads();
    unsigned short* hb = hsF + (size_t)bb * NQ * FQ;
    #pragma unroll
    for (int it = 0; it < 2; ++it) {
        int p = tid + it * 256;
        int f = p & 127, mc = p >> 7;
        us8 u;
        #pragma unroll
        for (int e = 0; e < 8; ++e)
            u[e] = f2bf(tile[mc * 8 + e][f] * iv[mc * 8 + e]);
        *(us8*)(hb + (size_t)((m0 >> 3) + mc) * 1024 + f * 8) = u;
    }
}

// ---- Kernel 3b (iters 1,2): isq from dpart; hsF from bf16 h ----
__global__ __launch_bounds__(256) void k_prep_bf16(const unsigned short* __restrict__ h,
                                                   const float* __restrict__ dpart,
                                                   float* __restrict__ isq,
                                                   unsigned short* __restrict__ hsF) {
    __shared__ float tile[32][129];
    __shared__ float iv[32];
    int r0 = blockIdx.x * 32;
    int bb = r0 >> 11;
    int m0 = r0 & (NQ - 1);
    int tid = threadIdx.x;
    if (tid < 32) {
        float s = 0.f;
        #pragma unroll
        for (int j = 0; j < 16; ++j)
            s += dpart[((size_t)j * 8 + bb) * NQ + m0 + tid];
        float v = 1.0f / sqrtf(s);
        iv[tid] = v;
        isq[r0 + tid] = v;
    }
    #pragma unroll
    for (int it = 0; it < 16; ++it) {
        int idx = tid + it * 256;
        int mi = idx >> 7, f = idx & 127;
        tile[mi][f] = bf2f(h[(size_t)(r0 + mi) * FQ + f]);
    }
    __syncthreads();
    unsigned short* hb = hsF + (size_t)bb * NQ * FQ;
    #pragma unroll
    for (int it = 0; it < 2; ++it) {
        int p = tid + it * 256;
        int f = p & 127, mc = p >> 7;
        us8 u;
        #pragma unroll
        for (int e = 0; e < 8; ++e)
            u[e] = f2bf(tile[mc * 8 + e][f] * iv[mc * 8 + e]);
        *(us8*)(hb + (size_t)((m0 >> 3) + mc) * 1024 + f * 8) = u;
    }
}

// ---- Kernel 4: hpart[kc] (bf16) = isq[n] * (adjF[:,Kchunk] @ hsF[Kchunk,:])
//      LDS-staged B via global_load_lds; NT loads of adjF; NT store of hpart. ----
template<int KC>
__global__ __launch_bounds__(256) void k_gemm2(const unsigned short* __restrict__ adjF,
                                               const unsigned short* __restrict__ hsF,
                                               const float* __restrict__ isq,
                                               unsigned short* __restrict__ hpart) {
    constexpr int KE = NQ / KC;
    constexpr int KS = KE / 32;
    constexpr int PH = 8;              // 64 KB LDS phase
    const size_t CS = (size_t)BQ * NQ * FQ;
    __shared__ unsigned short Bs[PH * 4 * 1024];

    int bid = blockIdx.x;
    int lb = (bid & 7) * (int)(gridDim.x >> 3) + (bid >> 3);   // XCD swizzle
    int kc = lb % KC;
    int rt = (lb / KC) & 15;
    int bb = lb / (KC * 16);
    int wid = threadIdx.x >> 6, lane = threadIdx.x & 63;
    int g = lane >> 4, c = lane & 15;
    int row0 = rt * 128 + wid * 32;

    const unsigned short* adjr = adjF + (size_t)bb * NQ * NQ + (size_t)(row0 >> 4) * NG
                                      + (size_t)((kc * KE) >> 3) * 128;
    const unsigned short* hb   = hsF + (size_t)bb * NQ * FQ + (size_t)((kc * KE) >> 3) * 1024;

    f32x4 acc[2][8];
    #pragma unroll
    for (int mi = 0; mi < 2; ++mi)
        #pragma unroll
        for (int i = 0; i < 8; ++i) acc[mi][i] = (f32x4){0.f, 0.f, 0.f, 0.f};

    for (int ph = 0; ph < KS / PH; ++ph) {
        __syncthreads();
        {
            const unsigned short* src = hb + (size_t)ph * (PH * 4 * 1024);
            #pragma unroll
            for (int it = 0; it < 16; ++it) {
                __builtin_amdgcn_global_load_lds(
                    (const __attribute__((address_space(1))) void*)(src + (size_t)(it * 256 + threadIdx.x) * 8),
                    (__attribute__((address_space(3))) void*)(Bs + (it * 256 + wid * 64) * 8),
                    16, 0, 0);
            }
        }
        __syncthreads();
        #pragma unroll
        for (int k2 = 0; k2 < PH; ++k2) {
            int kk = ph * PH + k2;
            short8 a0 = __builtin_nontemporal_load((const short8*)(adjr + (size_t)(kk * 4 + g) * 128 + c * 8));
            short8 a1 = __builtin_nontemporal_load((const short8*)(adjr + NG + (size_t)(kk * 4 + g) * 128 + c * 8));
            #pragma unroll
            for (int ct = 0; ct < 8; ++ct) {
                short8 bfr = *(const short8*)(Bs + (k2 * 4 + g) * 1024 + ct * 128 + c * 8);
                acc[0][ct] = __builtin_amdgcn_mfma_f32_16x16x32_bf16(a0, bfr, acc[0][ct], 0, 0, 0);
                acc[1][ct] = __builtin_amdgcn_mfma_f32_16x16x32_bf16(a1, bfr, acc[1][ct], 0, 0, 0);
            }
        }
    }

    unsigned short* hp = hpart + (size_t)kc * CS + (size_t)bb * NQ * FQ;
    #pragma unroll
    for (int mi = 0; mi < 2; ++mi) {
        float is[4];
        #pragma unroll
        for (int r = 0; r < 4; ++r) is[r] = isq[(size_t)bb * NQ + row0 + mi * 16 + g * 4 + r];
        #pragma unroll
        for (int ct = 0; ct < 8; ++ct)
            #pragma unroll
            for (int r = 0; r < 4; ++r)
                __builtin_nontemporal_store(f2bf(acc[mi][ct][r] * is[r]),
                    hp + (size_t)(row0 + mi * 16 + g * 4 + r) * FQ + ct * 16 + c);
    }
}

// ---- Kernel 5: out = (sum_kc hpart(bf16) + x) @ W ----
template<int KC>
__global__ __launch_bounds__(256) void k_out4(const unsigned short* __restrict__ hp,
                                              const float* __restrict__ x,
                                              const float* __restrict__ W,
                                              float* __restrict__ out) {
    const size_t CS = (size_t)BQ * NQ * FQ;
    __shared__ float hx[8][128];
    int r0 = blockIdx.x * 8;
    int tid = threadIdx.x;
    #pragma unroll
    for (int it = 0; it < 4; ++it) {
        int idx = tid + it * 256;
        int ri = idx >> 7, f = idx & 127;
        size_t gi = (size_t)(r0 + ri) * FQ + f;
        float s = x[gi];
        #pragma unroll
        for (int k = 0; k < KC; ++k) s += bf2f(hp[k * CS + gi]);
        hx[ri][f] = s;
    }
    __syncthreads();
    int o = tid & 127, half = tid >> 7;
    float acc[4] = {0.f, 0.f, 0.f, 0.f};
    for (int f = 0; f < 128; ++f) {
        float wv = W[f * 128 + o];
        #pragma unroll
        for (int j = 0; j < 4; ++j)
            acc[j] += hx[half * 4 + j][f] * wv;
    }
    #pragma unroll
    for (int j = 0; j < 4; ++j)
        out[(size_t)(r0 + half * 4 + j) * FQ + o] = acc[j];
}

template<int KC>
static void run_all(const float* x, const float* W, float* out,
                    unsigned short* adjF, unsigned short* xnF, unsigned short* hsF,
                    float* dpart, float* isq, unsigned short* h, unsigned short* hpart,
                    hipStream_t stream) {
    const float ts[3] = {0.05f, 0.1f, 0.15f};
    for (int i = 0; i < 3; ++i) {
        if (i == 0) k_rownorm<<<BQ * NQ / 16, 256, 0, stream>>>(x, xnF);
        else        k_rownorm4<KC><<<BQ * NQ / 16, 256, 0, stream>>>(hpart, h, xnF);
        k_adj<<<BQ * 256, 512, 0, stream>>>(xnF, adjF, dpart, ts[i]);
        if (i == 0) k_prep_f32 <<<BQ * NQ / 32, 256, 0, stream>>>(x, dpart, isq, hsF);
        else        k_prep_bf16<<<BQ * NQ / 32, 256, 0, stream>>>(h, dpart, isq, hsF);
        k_gemm2<KC><<<BQ * 16 * KC, 256, 0, stream>>>(adjF, hsF, isq, hpart);
    }
    k_out4<KC><<<BQ * NQ / 8, 256, 0, stream>>>(hpart, x, W, out);
}

extern "C" void kernel_launch(void* const* d_in, const int* in_sizes, int n_in,
                              void* d_out, int out_size, void* d_ws, size_t ws_size,
                              hipStream_t stream) {
    const float* x = (const float*)d_in[0];
    const float* W = (const float*)d_in[1];
    float* out = (float*)d_out;
    char* ws = (char*)d_ws;

    const size_t CS   = (size_t)BQ * NQ * FQ;
    const size_t oADJ = 0;
    const size_t oXN  = oADJ + (size_t)BQ * NQ * NQ * 2;      // 64 MiB
    const size_t oHST = oXN  + CS * 2;                        // +4 MiB
    const size_t oD   = oHST + CS * 2;                        // +4 MiB
    const size_t oISQ = oD   + (size_t)16 * BQ * NQ * 4;      // +1 MiB
    const size_t oH   = oISQ + (size_t)BQ * NQ * 4;           // +64 KiB
    const size_t oHP  = oH   + CS * 2;                        // +4 MiB (bf16 h)
    const size_t need1 = oHP + 1 * CS * 2;                    // bf16 partials
    const size_t need2 = oHP + 2 * CS * 2;
    const size_t need4 = oHP + 4 * CS * 2;

    unsigned short* adjF = (unsigned short*)(ws + oADJ);
    unsigned short* xnF  = (unsigned short*)(ws + oXN);
    unsigned short* hsF  = (unsigned short*)(ws + oHST);
    float* dpart = (float*)(ws + oD);
    float* isq   = (float*)(ws + oISQ);
    unsigned short* h     = (unsigned short*)(ws + oH);
    unsigned short* hpart = (unsigned short*)(ws + oHP);

    if (ws_size >= need4)
        run_all<4>(x, W, out, adjF, xnF, hsF, dpart, isq, h, hpart, stream);
    else if (ws_size >= need2)
        run_all<2>(x, W, out, adjF, xnF, hsF, dpart, isq, h, hpart, stream);
    else if (ws_size >= need1)
        run_all<1>(x, W, out, adjF, xnF, hsF, dpart, isq, h, hpart, stream);
    // else: workspace too small (diagnostic — output stays poisoned)
}

// Round 14
// 163.439 us; speedup vs baseline: 1.0974x; 1.0974x over previous
//
#include <hip/hip_runtime.h>
#include <hip/hip_bf16.h>
#include <cstdint>

#define BQ 8
#define NQ 2048
#define FQ 128
#define NG (NQ * 16)            // adjF n-group stride (elems)

typedef __attribute__((ext_vector_type(8))) short short8;
typedef __attribute__((ext_vector_type(4))) float f32x4;
typedef __attribute__((ext_vector_type(8))) unsigned short us8;
typedef __attribute__((ext_vector_type(2))) unsigned int u32x2;

__device__ __forceinline__ unsigned short f2bf(float f) {
    union { float f; unsigned int u; } c; c.f = f;
    unsigned int u = c.u;
    u = (u + 0x7FFFu + ((u >> 16) & 1u)) >> 16;   // RNE
    return (unsigned short)u;
}
__device__ __forceinline__ float bf2f(unsigned short u) {
    union { unsigned int i; float f; } c; c.i = (unsigned int)u << 16; return c.f;
}
__device__ __forceinline__ unsigned int cvtpk(float lo, float hi) {
    unsigned int r;
    asm("v_cvt_pk_bf16_f32 %0, %1, %2" : "=v"(r) : "v"(lo), "v"(hi));
    return r;
}

// Fragment layouts (per batch):
//   xnF : [n/16][k/8][n%16][k%8]   addr = (n>>4)*2048 + (k>>3)*128 + (n&15)*8 + (k&7)
//   adjF: [n/16][m/8][n%16][m%8]   addr = (n>>4)*NG   + (m>>3)*128 + (n&15)*8 + (m&7)
//   hsF : [m/8][f][m%8]            addr = (m>>3)*1024 + f*8 + (m&7)
// hpart, h are bf16 row-major [n][f].
// r14: NT hints reverted (r13 regression: adjF round-trip lives in L2/L3).
// k_adj swizzle REMOVED: batch-per-XCD concentration churned one XCD's 4 MiB L2
// with an 8 MiB write stream; unswizzled spreads writes over all 8 L2s.

// ---- Kernel 1a: row L2-normalize x -> xnF (16 rows/block) ----
__global__ __launch_bounds__(256) void k_rownorm(const float* __restrict__ h,
                                                 unsigned short* __restrict__ xnF) {
    int t = threadIdx.x;
    int rl = t >> 4, j = t & 15;
    size_t row = (size_t)blockIdx.x * 16 + rl;
    const float* hr = h + row * FQ + j * 8;
    float v[8];
    #pragma unroll
    for (int e = 0; e < 8; ++e) v[e] = hr[e];
    float s = 0.f;
    #pragma unroll
    for (int e = 0; e < 8; ++e) s += v[e] * v[e];
    s += __shfl_xor(s, 1, 64);
    s += __shfl_xor(s, 2, 64);
    s += __shfl_xor(s, 4, 64);
    s += __shfl_xor(s, 8, 64);
    float inv = 1.0f / fmaxf(sqrtf(s), 1e-8f);
    us8 u;
    #pragma unroll
    for (int e = 0; e < 8; ++e) u[e] = f2bf(v[e] * inv);
    *(us8*)(xnF + (size_t)blockIdx.x * 2048 + j * 128 + rl * 8) = u;
}

// ---- Kernel 1b: reduce bf16 K-split partials -> bf16 h, normalize -> xnF ----
template<int KC>
__global__ __launch_bounds__(256) void k_rownorm4(const unsigned short* __restrict__ hp,
                                                  unsigned short* __restrict__ hout,
                                                  unsigned short* __restrict__ xnF) {
    const size_t CS = (size_t)BQ * NQ * FQ;
    int t = threadIdx.x;
    int rl = t >> 4, j = t & 15;
    size_t row = (size_t)blockIdx.x * 16 + rl;
    size_t o = row * FQ + j * 8;
    float v[8] = {0.f, 0.f, 0.f, 0.f, 0.f, 0.f, 0.f, 0.f};
    #pragma unroll
    for (int k = 0; k < KC; ++k) {
        us8 pv = *(const us8*)(hp + k * CS + o);
        #pragma unroll
        for (int e = 0; e < 8; ++e) v[e] += bf2f(pv[e]);
    }
    us8 hw;
    #pragma unroll
    for (int e = 0; e < 8; ++e) hw[e] = f2bf(v[e]);
    *(us8*)(hout + o) = hw;
    float s = 0.f;
    #pragma unroll
    for (int e = 0; e < 8; ++e) s += v[e] * v[e];
    s += __shfl_xor(s, 1, 64);
    s += __shfl_xor(s, 2, 64);
    s += __shfl_xor(s, 4, 64);
    s += __shfl_xor(s, 8, 64);
    float inv = 1.0f / fmaxf(sqrtf(s), 1e-8f);
    us8 u;
    #pragma unroll
    for (int e = 0; e < 8; ++e) u[e] = f2bf(v[e] * inv);
    *(us8*)(xnF + (size_t)blockIdx.x * 2048 + j * 128 + rl * 8) = u;
}

// ---- Kernel 2: S = xn@xn^T, threshold, transposed store to adjF, dpart sums.
//      128x128 tile per 512-thr block; NO XCD swizzle (r14). ----
__global__ __launch_bounds__(512) void k_adj(const unsigned short* __restrict__ xnF,
                                             unsigned short* __restrict__ adjF,
                                             float* __restrict__ dpart, float t) {
    int blk = blockIdx.x;                      // r14: unswizzled
    int bb  = blk >> 8;
    int ij  = blk & 255;
    int I   = ij >> 4, J = ij & 15;
    int wid = threadIdx.x >> 6, lane = threadIdx.x & 63;
    int wr = wid >> 1, wc = wid & 1;
    int g = lane >> 4, c = lane & 15;

    const unsigned short* xb = xnF + (size_t)bb * NQ * FQ;
    int rowb = I * 128 + wr * 32;
    int colb = J * 128 + wc * 64;

    short8 a[2][4];
    #pragma unroll
    for (int mi = 0; mi < 2; ++mi)
        #pragma unroll
        for (int ks = 0; ks < 4; ++ks)
            a[mi][ks] = *(const short8*)(xb + (size_t)((rowb >> 4) + mi) * 2048 + (ks * 4 + g) * 128 + c * 8);

    f32x4 acc[2][4];
    #pragma unroll
    for (int mi = 0; mi < 2; ++mi)
        #pragma unroll
        for (int ni = 0; ni < 4; ++ni) acc[mi][ni] = (f32x4){0.f, 0.f, 0.f, 0.f};

    #pragma unroll
    for (int ni = 0; ni < 4; ++ni) {
        short8 b[4];
        #pragma unroll
        for (int ks = 0; ks < 4; ++ks)
            b[ks] = *(const short8*)(xb + (size_t)((colb >> 4) + ni) * 2048 + (ks * 4 + g) * 128 + c * 8);
        #pragma unroll
        for (int mi = 0; mi < 2; ++mi)
            #pragma unroll
            for (int ks = 0; ks < 4; ++ks)
                acc[mi][ni] = __builtin_amdgcn_mfma_f32_16x16x32_bf16(a[mi][ks], b[ks], acc[mi][ni], 0, 0, 0);
    }

    unsigned short* adjb = adjF + (size_t)bb * NQ * NQ;
    __shared__ float dsm[2][128];
    float dl[2][4];
    #pragma unroll
    for (int mi = 0; mi < 2; ++mi)
        #pragma unroll
        for (int r = 0; r < 4; ++r) dl[mi][r] = 0.f;

    #pragma unroll
    for (int mi = 0; mi < 2; ++mi)
        #pragma unroll
        for (int ni = 0; ni < 4; ++ni) {
            f32x4 v = acc[mi][ni];
            float x0 = (v[0] > t) ? v[0] : 0.0f;   // strict threshold in f32
            float x1 = (v[1] > t) ? v[1] : 0.0f;
            float x2 = (v[2] > t) ? v[2] : 0.0f;
            float x3 = (v[3] > t) ? v[3] : 0.0f;
            dl[mi][0] += x0; dl[mi][1] += x1; dl[mi][2] += x2; dl[mi][3] += x3;
            u32x2 u;
            u[0] = cvtpk(x0, x1);
            u[1] = cvtpk(x2, x3);
            *(u32x2*)(adjb + (size_t)((colb >> 4) + ni) * NG
                           + (size_t)((rowb >> 3) + mi * 2 + (g >> 1)) * 128
                           + c * 8 + (g & 1) * 4) = u;
        }

    #pragma unroll
    for (int mi = 0; mi < 2; ++mi)
        #pragma unroll
        for (int r = 0; r < 4; ++r) {
            float s = dl[mi][r];
            s += __shfl_xor(s, 1, 64);
            s += __shfl_xor(s, 2, 64);
            s += __shfl_xor(s, 4, 64);
            s += __shfl_xor(s, 8, 64);
            dl[mi][r] = s;
        }
    if (c == 0) {
        #pragma unroll
        for (int mi = 0; mi < 2; ++mi)
            #pragma unroll
            for (int r = 0; r < 4; ++r)
                dsm[wc][wr * 32 + mi * 16 + g * 4 + r] = dl[mi][r];
    }
    __syncthreads();
    int tid = threadIdx.x;
    if (tid < 128)
        dpart[((size_t)J * 8 + bb) * NQ + I * 128 + tid] = dsm[0][tid] + dsm[1][tid];
}

// ---- Kernel 3a (iter 0): isq from dpart; hsF from f32 x ----
__global__ __launch_bounds__(256) void k_prep_f32(const float* __restrict__ h,
                                                  const float* __restrict__ dpart,
                                                  float* __restrict__ isq,
                                                  unsigned short* __restrict__ hsF) {
    __shared__ float tile[32][129];
    __shared__ float iv[32];
    int r0 = blockIdx.x * 32;
    int bb = r0 >> 11;
    int m0 = r0 & (NQ - 1);
    int tid = threadIdx.x;
    if (tid < 32) {
        float s = 0.f;
        #pragma unroll
        for (int j = 0; j < 16; ++j)
            s += dpart[((size_t)j * 8 + bb) * NQ + m0 + tid];
        float v = 1.0f / sqrtf(s);
        iv[tid] = v;
        isq[r0 + tid] = v;
    }
    #pragma unroll
    for (int it = 0; it < 16; ++it) {
        int idx = tid + it * 256;
        int mi = idx >> 7, f = idx & 127;
        tile[mi][f] = h[(size_t)(r0 + mi) * FQ + f];
    }
    __syncthreads();
    unsigned short* hb = hsF + (size_t)bb * NQ * FQ;
    #pragma unroll
    for (int it = 0; it < 2; ++it) {
        int p = tid + it * 256;
        int f = p & 127, mc = p >> 7;
        us8 u;
        #pragma unroll
        for (int e = 0; e < 8; ++e)
            u[e] = f2bf(tile[mc * 8 + e][f] * iv[mc * 8 + e]);
        *(us8*)(hb + (size_t)((m0 >> 3) + mc) * 1024 + f * 8) = u;
    }
}

// ---- Kernel 3b (iters 1,2): isq from dpart; hsF from bf16 h ----
__global__ __launch_bounds__(256) void k_prep_bf16(const unsigned short* __restrict__ h,
                                                   const float* __restrict__ dpart,
                                                   float* __restrict__ isq,
                                                   unsigned short* __restrict__ hsF) {
    __shared__ float tile[32][129];
    __shared__ float iv[32];
    int r0 = blockIdx.x * 32;
    int bb = r0 >> 11;
    int m0 = r0 & (NQ - 1);
    int tid = threadIdx.x;
    if (tid < 32) {
        float s = 0.f;
        #pragma unroll
        for (int j = 0; j < 16; ++j)
            s += dpart[((size_t)j * 8 + bb) * NQ + m0 + tid];
        float v = 1.0f / sqrtf(s);
        iv[tid] = v;
        isq[r0 + tid] = v;
    }
    #pragma unroll
    for (int it = 0; it < 16; ++it) {
        int idx = tid + it * 256;
        int mi = idx >> 7, f = idx & 127;
        tile[mi][f] = bf2f(h[(size_t)(r0 + mi) * FQ + f]);
    }
    __syncthreads();
    unsigned short* hb = hsF + (size_t)bb * NQ * FQ;
    #pragma unroll
    for (int it = 0; it < 2; ++it) {
        int p = tid + it * 256;
        int f = p & 127, mc = p >> 7;
        us8 u;
        #pragma unroll
        for (int e = 0; e < 8; ++e)
            u[e] = f2bf(tile[mc * 8 + e][f] * iv[mc * 8 + e]);
        *(us8*)(hb + (size_t)((m0 >> 3) + mc) * 1024 + f * 8) = u;
    }
}

// ---- Kernel 4: hpart[kc] (bf16) = isq[n] * (adjF[:,Kchunk] @ hsF[Kchunk,:])
//      LDS-staged B via global_load_lds, fat 32-row waves, 128 rows/block. ----
template<int KC>
__global__ __launch_bounds__(256) void k_gemm2(const unsigned short* __restrict__ adjF,
                                               const unsigned short* __restrict__ hsF,
                                               const float* __restrict__ isq,
                                               unsigned short* __restrict__ hpart) {
    constexpr int KE = NQ / KC;
    constexpr int KS = KE / 32;
    constexpr int PH = 8;              // 64 KB LDS phase
    const size_t CS = (size_t)BQ * NQ * FQ;
    __shared__ unsigned short Bs[PH * 4 * 1024];

    int bid = blockIdx.x;
    int lb = (bid & 7) * (int)(gridDim.x >> 3) + (bid >> 3);   // XCD swizzle
    int kc = lb % KC;
    int rt = (lb / KC) & 15;
    int bb = lb / (KC * 16);
    int wid = threadIdx.x >> 6, lane = threadIdx.x & 63;
    int g = lane >> 4, c = lane & 15;
    int row0 = rt * 128 + wid * 32;

    const unsigned short* adjr = adjF + (size_t)bb * NQ * NQ + (size_t)(row0 >> 4) * NG
                                      + (size_t)((kc * KE) >> 3) * 128;
    const unsigned short* hb   = hsF + (size_t)bb * NQ * FQ + (size_t)((kc * KE) >> 3) * 1024;

    f32x4 acc[2][8];
    #pragma unroll
    for (int mi = 0; mi < 2; ++mi)
        #pragma unroll
        for (int i = 0; i < 8; ++i) acc[mi][i] = (f32x4){0.f, 0.f, 0.f, 0.f};

    for (int ph = 0; ph < KS / PH; ++ph) {
        __syncthreads();
        {
            const unsigned short* src = hb + (size_t)ph * (PH * 4 * 1024);
            #pragma unroll
            for (int it = 0; it < 16; ++it) {
                __builtin_amdgcn_global_load_lds(
                    (const __attribute__((address_space(1))) void*)(src + (size_t)(it * 256 + threadIdx.x) * 8),
                    (__attribute__((address_space(3))) void*)(Bs + (it * 256 + wid * 64) * 8),
                    16, 0, 0);
            }
        }
        __syncthreads();
        #pragma unroll
        for (int k2 = 0; k2 < PH; ++k2) {
            int kk = ph * PH + k2;
            short8 a0 = *(const short8*)(adjr + (size_t)(kk * 4 + g) * 128 + c * 8);
            short8 a1 = *(const short8*)(adjr + NG + (size_t)(kk * 4 + g) * 128 + c * 8);
            #pragma unroll
            for (int ct = 0; ct < 8; ++ct) {
                short8 bfr = *(const short8*)(Bs + (k2 * 4 + g) * 1024 + ct * 128 + c * 8);
                acc[0][ct] = __builtin_amdgcn_mfma_f32_16x16x32_bf16(a0, bfr, acc[0][ct], 0, 0, 0);
                acc[1][ct] = __builtin_amdgcn_mfma_f32_16x16x32_bf16(a1, bfr, acc[1][ct], 0, 0, 0);
            }
        }
    }

    unsigned short* hp = hpart + (size_t)kc * CS + (size_t)bb * NQ * FQ;
    #pragma unroll
    for (int mi = 0; mi < 2; ++mi) {
        float is[4];
        #pragma unroll
        for (int r = 0; r < 4; ++r) is[r] = isq[(size_t)bb * NQ + row0 + mi * 16 + g * 4 + r];
        #pragma unroll
        for (int ct = 0; ct < 8; ++ct)
            #pragma unroll
            for (int r = 0; r < 4; ++r)
                hp[(size_t)(row0 + mi * 16 + g * 4 + r) * FQ + ct * 16 + c] = f2bf(acc[mi][ct][r] * is[r]);
    }
}

// ---- Kernel 5: out = (sum_kc hpart(bf16) + x) @ W ----
template<int KC>
__global__ __launch_bounds__(256) void k_out4(const unsigned short* __restrict__ hp,
                                              const float* __restrict__ x,
                                              const float* __restrict__ W,
                                              float* __restrict__ out) {
    const size_t CS = (size_t)BQ * NQ * FQ;
    __shared__ float hx[8][128];
    int r0 = blockIdx.x * 8;
    int tid = threadIdx.x;
    #pragma unroll
    for (int it = 0; it < 4; ++it) {
        int idx = tid + it * 256;
        int ri = idx >> 7, f = idx & 127;
        size_t gi = (size_t)(r0 + ri) * FQ + f;
        float s = x[gi];
        #pragma unroll
        for (int k = 0; k < KC; ++k) s += bf2f(hp[k * CS + gi]);
        hx[ri][f] = s;
    }
    __syncthreads();
    int o = tid & 127, half = tid >> 7;
    float acc[4] = {0.f, 0.f, 0.f, 0.f};
    for (int f = 0; f < 128; ++f) {
        float wv = W[f * 128 + o];
        #pragma unroll
        for (int j = 0; j < 4; ++j)
            acc[j] += hx[half * 4 + j][f] * wv;
    }
    #pragma unroll
    for (int j = 0; j < 4; ++j)
        out[(size_t)(r0 + half * 4 + j) * FQ + o] = acc[j];
}

template<int KC>
static void run_all(const float* x, const float* W, float* out,
                    unsigned short* adjF, unsigned short* xnF, unsigned short* hsF,
                    float* dpart, float* isq, unsigned short* h, unsigned short* hpart,
                    hipStream_t stream) {
    const float ts[3] = {0.05f, 0.1f, 0.15f};
    for (int i = 0; i < 3; ++i) {
        if (i == 0) k_rownorm<<<BQ * NQ / 16, 256, 0, stream>>>(x, xnF);
        else        k_rownorm4<KC><<<BQ * NQ / 16, 256, 0, stream>>>(hpart, h, xnF);
        k_adj<<<BQ * 256, 512, 0, stream>>>(xnF, adjF, dpart, ts[i]);
        if (i == 0) k_prep_f32 <<<BQ * NQ / 32, 256, 0, stream>>>(x, dpart, isq, hsF);
        else        k_prep_bf16<<<BQ * NQ / 32, 256, 0, stream>>>(h, dpart, isq, hsF);
        k_gemm2<KC><<<BQ * 16 * KC, 256, 0, stream>>>(adjF, hsF, isq, hpart);
    }
    k_out4<KC><<<BQ * NQ / 8, 256, 0, stream>>>(hpart, x, W, out);
}

extern "C" void kernel_launch(void* const* d_in, const int* in_sizes, int n_in,
                              void* d_out, int out_size, void* d_ws, size_t ws_size,
                              hipStream_t stream) {
    const float* x = (const float*)d_in[0];
    const float* W = (const float*)d_in[1];
    float* out = (float*)d_out;
    char* ws = (char*)d_ws;

    const size_t CS   = (size_t)BQ * NQ * FQ;
    const size_t oADJ = 0;
    const size_t oXN  = oADJ + (size_t)BQ * NQ * NQ * 2;      // 64 MiB
    const size_t oHST = oXN  + CS * 2;                        // +4 MiB
    const size_t oD   = oHST + CS * 2;                        // +4 MiB
    const size_t oISQ = oD   + (size_t)16 * BQ * NQ * 4;      // +1 MiB
    const size_t oH   = oISQ + (size_t)BQ * NQ * 4;           // +64 KiB
    const size_t oHP  = oH   + CS * 2;                        // +4 MiB (bf16 h)
    const size_t need1 = oHP + 1 * CS * 2;                    // bf16 partials
    const size_t need2 = oHP + 2 * CS * 2;
    const size_t need4 = oHP + 4 * CS * 2;

    unsigned short* adjF = (unsigned short*)(ws + oADJ);
    unsigned short* xnF  = (unsigned short*)(ws + oXN);
    unsigned short* hsF  = (unsigned short*)(ws + oHST);
    float* dpart = (float*)(ws + oD);
    float* isq   = (float*)(ws + oISQ);
    unsigned short* h     = (unsigned short*)(ws + oH);
    unsigned short* hpart = (unsigned short*)(ws + oHP);

    if (ws_size >= need4)
        run_all<4>(x, W, out, adjF, xnF, hsF, dpart, isq, h, hpart, stream);
    else if (ws_size >= need2)
        run_all<2>(x, W, out, adjF, xnF, hsF, dpart, isq, h, hpart, stream);
    else if (ws_size >= need1)
        run_all<1>(x, W, out, adjF, xnF, hsF, dpart, isq, h, hpart, stream);
    // else: workspace too small (diagnostic — output stays poisoned)
}

// Round 15
// 152.748 us; speedup vs baseline: 1.1742x; 1.0700x over previous
//
#include <hip/hip_runtime.h>
#include <hip/hip_bf16.h>
#include <cstdint>

#define BQ 8
#define NQ 2048
#define FQ 128
#define NG (NQ * 16)            // adjF n-group stride in BYTES (fp8, r15)
#define HSS 256.0f              // hs fp8 scale

typedef __attribute__((ext_vector_type(8))) short short8;
typedef __attribute__((ext_vector_type(4))) float f32x4;
typedef __attribute__((ext_vector_type(8))) unsigned short us8;
typedef __attribute__((ext_vector_type(2))) unsigned int u32x2;

__device__ __forceinline__ unsigned short f2bf(float f) {
    union { float f; unsigned int u; } c; c.f = f;
    unsigned int u = c.u;
    u = (u + 0x7FFFu + ((u >> 16) & 1u)) >> 16;   // RNE
    return (unsigned short)u;
}
__device__ __forceinline__ float bf2f(unsigned short u) {
    union { unsigned int i; float f; } c; c.i = (unsigned int)u << 16; return c.f;
}
// pack 2 f32 -> 2 e4m3 bytes into low / high word half
__device__ __forceinline__ unsigned int pk8lo(float a, float b, unsigned int old) {
    return (unsigned int)__builtin_amdgcn_cvt_pk_fp8_f32(a, b, (int)old, false);
}
__device__ __forceinline__ unsigned int pk8hi(float a, float b, unsigned int old) {
    return (unsigned int)__builtin_amdgcn_cvt_pk_fp8_f32(a, b, (int)old, true);
}

// Layouts (per batch):
//   xnF : bf16 [n/16][k/8][n%16][k%8]  elem addr = (n>>4)*2048 + (k>>3)*128 + (n&15)*8 + (k&7)
//   adjF: fp8  [n/16][m/8][n%16][m%8]  BYTE addr = (n>>4)*NG + (m>>3)*128 + (n&15)*8 + (m&7)
//   hsF : fp8  [m/8][f][m%8]           BYTE addr = (m>>3)*1024 + f*8 + (m&7); value = hs*HSS
// hpart, h: bf16 row-major [n][f].
// r15: adjacency + hs in e4m3 fp8 -> halves the dominant 128 MiB/iter round-trip;
// gemm2 uses mfma_f32_16x16x32_fp8_fp8. Threshold/dpart/isq stay f32.

// ---- Kernel 1a: row L2-normalize x -> xnF (16 rows/block) ----
__global__ __launch_bounds__(256) void k_rownorm(const float* __restrict__ h,
                                                 unsigned short* __restrict__ xnF) {
    int t = threadIdx.x;
    int rl = t >> 4, j = t & 15;
    size_t row = (size_t)blockIdx.x * 16 + rl;
    const float* hr = h + row * FQ + j * 8;
    float v[8];
    #pragma unroll
    for (int e = 0; e < 8; ++e) v[e] = hr[e];
    float s = 0.f;
    #pragma unroll
    for (int e = 0; e < 8; ++e) s += v[e] * v[e];
    s += __shfl_xor(s, 1, 64);
    s += __shfl_xor(s, 2, 64);
    s += __shfl_xor(s, 4, 64);
    s += __shfl_xor(s, 8, 64);
    float inv = 1.0f / fmaxf(sqrtf(s), 1e-8f);
    us8 u;
    #pragma unroll
    for (int e = 0; e < 8; ++e) u[e] = f2bf(v[e] * inv);
    *(us8*)(xnF + (size_t)blockIdx.x * 2048 + j * 128 + rl * 8) = u;
}

// ---- Kernel 1b: reduce bf16 K-split partials -> bf16 h, normalize -> xnF ----
template<int KC>
__global__ __launch_bounds__(256) void k_rownorm4(const unsigned short* __restrict__ hp,
                                                  unsigned short* __restrict__ hout,
                                                  unsigned short* __restrict__ xnF) {
    const size_t CS = (size_t)BQ * NQ * FQ;
    int t = threadIdx.x;
    int rl = t >> 4, j = t & 15;
    size_t row = (size_t)blockIdx.x * 16 + rl;
    size_t o = row * FQ + j * 8;
    float v[8] = {0.f, 0.f, 0.f, 0.f, 0.f, 0.f, 0.f, 0.f};
    #pragma unroll
    for (int k = 0; k < KC; ++k) {
        us8 pv = *(const us8*)(hp + k * CS + o);
        #pragma unroll
        for (int e = 0; e < 8; ++e) v[e] += bf2f(pv[e]);
    }
    us8 hw;
    #pragma unroll
    for (int e = 0; e < 8; ++e) hw[e] = f2bf(v[e]);
    *(us8*)(hout + o) = hw;
    float s = 0.f;
    #pragma unroll
    for (int e = 0; e < 8; ++e) s += v[e] * v[e];
    s += __shfl_xor(s, 1, 64);
    s += __shfl_xor(s, 2, 64);
    s += __shfl_xor(s, 4, 64);
    s += __shfl_xor(s, 8, 64);
    float inv = 1.0f / fmaxf(sqrtf(s), 1e-8f);
    us8 u;
    #pragma unroll
    for (int e = 0; e < 8; ++e) u[e] = f2bf(v[e] * inv);
    *(us8*)(xnF + (size_t)blockIdx.x * 2048 + j * 128 + rl * 8) = u;
}

// ---- Kernel 2: S = xn@xn^T (bf16 MFMA), threshold f32, transposed fp8 store,
//      dpart sums. 128x128 tile per 512-thr block, XCD-swizzled (r12 config). ----
__global__ __launch_bounds__(512) void k_adj(const unsigned short* __restrict__ xnF,
                                             unsigned char* __restrict__ adjF,
                                             float* __restrict__ dpart, float t) {
    int bid = blockIdx.x;
    int blk = (bid & 7) * (int)(gridDim.x >> 3) + (bid >> 3);   // XCD swizzle
    int bb  = blk >> 8;
    int ij  = blk & 255;
    int I   = ij >> 4, J = ij & 15;
    int wid = threadIdx.x >> 6, lane = threadIdx.x & 63;
    int wr = wid >> 1, wc = wid & 1;
    int g = lane >> 4, c = lane & 15;

    const unsigned short* xb = xnF + (size_t)bb * NQ * FQ;
    int rowb = I * 128 + wr * 32;
    int colb = J * 128 + wc * 64;

    short8 a[2][4];
    #pragma unroll
    for (int mi = 0; mi < 2; ++mi)
        #pragma unroll
        for (int ks = 0; ks < 4; ++ks)
            a[mi][ks] = *(const short8*)(xb + (size_t)((rowb >> 4) + mi) * 2048 + (ks * 4 + g) * 128 + c * 8);

    f32x4 acc[2][4];
    #pragma unroll
    for (int mi = 0; mi < 2; ++mi)
        #pragma unroll
        for (int ni = 0; ni < 4; ++ni) acc[mi][ni] = (f32x4){0.f, 0.f, 0.f, 0.f};

    #pragma unroll
    for (int ni = 0; ni < 4; ++ni) {
        short8 b[4];
        #pragma unroll
        for (int ks = 0; ks < 4; ++ks)
            b[ks] = *(const short8*)(xb + (size_t)((colb >> 4) + ni) * 2048 + (ks * 4 + g) * 128 + c * 8);
        #pragma unroll
        for (int mi = 0; mi < 2; ++mi)
            #pragma unroll
            for (int ks = 0; ks < 4; ++ks)
                acc[mi][ni] = __builtin_amdgcn_mfma_f32_16x16x32_bf16(a[mi][ks], b[ks], acc[mi][ni], 0, 0, 0);
    }

    unsigned char* adjb = adjF + (size_t)bb * NQ * NQ;   // 1 B/elem
    __shared__ float dsm[2][128];
    float dl[2][4];
    #pragma unroll
    for (int mi = 0; mi < 2; ++mi)
        #pragma unroll
        for (int r = 0; r < 4; ++r) dl[mi][r] = 0.f;

    #pragma unroll
    for (int mi = 0; mi < 2; ++mi)
        #pragma unroll
        for (int ni = 0; ni < 4; ++ni) {
            f32x4 v = acc[mi][ni];
            float x0 = (v[0] > t) ? v[0] : 0.0f;   // strict threshold in f32
            float x1 = (v[1] > t) ? v[1] : 0.0f;
            float x2 = (v[2] > t) ? v[2] : 0.0f;
            float x3 = (v[3] > t) ? v[3] : 0.0f;
            dl[mi][0] += x0; dl[mi][1] += x1; dl[mi][2] += x2; dl[mi][3] += x3;
            unsigned int u = pk8lo(x0, x1, 0u);
            u = pk8hi(x2, x3, u);
            // mirror-transposed (S symmetric): element (row, col) stored at (n=col, m=row)
            *(unsigned int*)(adjb + (size_t)((colb >> 4) + ni) * NG
                                  + (size_t)((rowb >> 3) + mi * 2 + (g >> 1)) * 128
                                  + c * 8 + (g & 1) * 4) = u;
        }

    #pragma unroll
    for (int mi = 0; mi < 2; ++mi)
        #pragma unroll
        for (int r = 0; r < 4; ++r) {
            float s = dl[mi][r];
            s += __shfl_xor(s, 1, 64);
            s += __shfl_xor(s, 2, 64);
            s += __shfl_xor(s, 4, 64);
            s += __shfl_xor(s, 8, 64);
            dl[mi][r] = s;
        }
    if (c == 0) {
        #pragma unroll
        for (int mi = 0; mi < 2; ++mi)
            #pragma unroll
            for (int r = 0; r < 4; ++r)
                dsm[wc][wr * 32 + mi * 16 + g * 4 + r] = dl[mi][r];
    }
    __syncthreads();
    int tid = threadIdx.x;
    if (tid < 128)
        dpart[((size_t)J * 8 + bb) * NQ + I * 128 + tid] = dsm[0][tid] + dsm[1][tid];
}

// ---- Kernel 3a (iter 0): isq from dpart; hsF (fp8, xHSS) from f32 x ----
__global__ __launch_bounds__(256) void k_prep_f32(const float* __restrict__ h,
                                                  const float* __restrict__ dpart,
                                                  float* __restrict__ isq,
                                                  unsigned char* __restrict__ hsF) {
    __shared__ float tile[32][129];
    __shared__ float iv[32];
    int r0 = blockIdx.x * 32;
    int bb = r0 >> 11;
    int m0 = r0 & (NQ - 1);
    int tid = threadIdx.x;
    if (tid < 32) {
        float s = 0.f;
        #pragma unroll
        for (int j = 0; j < 16; ++j)
            s += dpart[((size_t)j * 8 + bb) * NQ + m0 + tid];
        float v = 1.0f / sqrtf(s);
        iv[tid] = v;
        isq[r0 + tid] = v;
    }
    #pragma unroll
    for (int it = 0; it < 16; ++it) {
        int idx = tid + it * 256;
        int mi = idx >> 7, f = idx & 127;
        tile[mi][f] = h[(size_t)(r0 + mi) * FQ + f];
    }
    __syncthreads();
    unsigned char* hb = hsF + (size_t)bb * NQ * FQ;
    #pragma unroll
    for (int it = 0; it < 2; ++it) {
        int p = tid + it * 256;
        int f = p & 127, mc = p >> 7;
        float sv[8];
        #pragma unroll
        for (int e = 0; e < 8; ++e)
            sv[e] = tile[mc * 8 + e][f] * iv[mc * 8 + e] * HSS;
        u32x2 u;
        u[0] = pk8hi(sv[2], sv[3], pk8lo(sv[0], sv[1], 0u));
        u[1] = pk8hi(sv[6], sv[7], pk8lo(sv[4], sv[5], 0u));
        *(u32x2*)(hb + (size_t)((m0 >> 3) + mc) * 1024 + f * 8) = u;
    }
}

// ---- Kernel 3b (iters 1,2): isq from dpart; hsF (fp8) from bf16 h ----
__global__ __launch_bounds__(256) void k_prep_bf16(const unsigned short* __restrict__ h,
                                                   const float* __restrict__ dpart,
                                                   float* __restrict__ isq,
                                                   unsigned char* __restrict__ hsF) {
    __shared__ float tile[32][129];
    __shared__ float iv[32];
    int r0 = blockIdx.x * 32;
    int bb = r0 >> 11;
    int m0 = r0 & (NQ - 1);
    int tid = threadIdx.x;
    if (tid < 32) {
        float s = 0.f;
        #pragma unroll
        for (int j = 0; j < 16; ++j)
            s += dpart[((size_t)j * 8 + bb) * NQ + m0 + tid];
        float v = 1.0f / sqrtf(s);
        iv[tid] = v;
        isq[r0 + tid] = v;
    }
    #pragma unroll
    for (int it = 0; it < 16; ++it) {
        int idx = tid + it * 256;
        int mi = idx >> 7, f = idx & 127;
        tile[mi][f] = bf2f(h[(size_t)(r0 + mi) * FQ + f]);
    }
    __syncthreads();
    unsigned char* hb = hsF + (size_t)bb * NQ * FQ;
    #pragma unroll
    for (int it = 0; it < 2; ++it) {
        int p = tid + it * 256;
        int f = p & 127, mc = p >> 7;
        float sv[8];
        #pragma unroll
        for (int e = 0; e < 8; ++e)
            sv[e] = tile[mc * 8 + e][f] * iv[mc * 8 + e] * HSS;
        u32x2 u;
        u[0] = pk8hi(sv[2], sv[3], pk8lo(sv[0], sv[1], 0u));
        u[1] = pk8hi(sv[6], sv[7], pk8lo(sv[4], sv[5], 0u));
        *(u32x2*)(hb + (size_t)((m0 >> 3) + mc) * 1024 + f * 8) = u;
    }
}

// ---- Kernel 4: hpart[kc](bf16) = isq/HSS * (adjF_fp8 @ hsF_fp8), fp8 MFMA.
//      LDS-staged B (32 KB phases via global_load_lds), 32-row waves, 128 rows/blk. ----
template<int KC>
__global__ __launch_bounds__(256) void k_gemm2(const unsigned char* __restrict__ adjF,
                                               const unsigned char* __restrict__ hsF,
                                               const float* __restrict__ isq,
                                               unsigned short* __restrict__ hpart) {
    constexpr int KE = NQ / KC;
    constexpr int KS = KE / 32;
    constexpr int PH = 8;              // 32 KB LDS phase (PH*4 m-groups x 1024 B)
    const size_t CS = (size_t)BQ * NQ * FQ;
    __shared__ unsigned char Bs[PH * 4 * 1024];

    int bid = blockIdx.x;
    int lb = (bid & 7) * (int)(gridDim.x >> 3) + (bid >> 3);   // XCD swizzle
    int kc = lb % KC;
    int rt = (lb / KC) & 15;
    int bb = lb / (KC * 16);
    int wid = threadIdx.x >> 6, lane = threadIdx.x & 63;
    int g = lane >> 4, c = lane & 15;
    int row0 = rt * 128 + wid * 32;

    const unsigned char* adjr = adjF + (size_t)bb * NQ * NQ + (size_t)(row0 >> 4) * NG
                                     + (size_t)((kc * KE) >> 3) * 128;
    const unsigned char* hb   = hsF + (size_t)bb * NQ * FQ + (size_t)((kc * KE) >> 3) * 1024;

    f32x4 acc[2][8];
    #pragma unroll
    for (int mi = 0; mi < 2; ++mi)
        #pragma unroll
        for (int i = 0; i < 8; ++i) acc[mi][i] = (f32x4){0.f, 0.f, 0.f, 0.f};

    for (int ph = 0; ph < KS / PH; ++ph) {
        __syncthreads();     // previous phase's readers done before overwrite
        {
            const unsigned char* src = hb + (size_t)ph * (PH * 4 * 1024);
            #pragma unroll
            for (int it = 0; it < 8; ++it) {
                __builtin_amdgcn_global_load_lds(
                    (const __attribute__((address_space(1))) void*)(src + (size_t)(it * 256 + threadIdx.x) * 16),
                    (__attribute__((address_space(3))) void*)(Bs + (it * 256 + wid * 64) * 16),
                    16, 0, 0);
            }
        }
        __syncthreads();     // compiler drains vmcnt before barrier
        #pragma unroll
        for (int k2 = 0; k2 < PH; ++k2) {
            int kk = ph * PH + k2;
            long a0 = *(const long*)(adjr + (size_t)(kk * 4 + g) * 128 + c * 8);
            long a1 = *(const long*)(adjr + NG + (size_t)(kk * 4 + g) * 128 + c * 8);
            #pragma unroll
            for (int ct = 0; ct < 8; ++ct) {
                long bfr = *(const long*)(Bs + (k2 * 4 + g) * 1024 + (ct * 16 + c) * 8);
                acc[0][ct] = __builtin_amdgcn_mfma_f32_16x16x32_fp8_fp8(a0, bfr, acc[0][ct], 0, 0, 0);
                acc[1][ct] = __builtin_amdgcn_mfma_f32_16x16x32_fp8_fp8(a1, bfr, acc[1][ct], 0, 0, 0);
            }
        }
    }

    unsigned short* hp = hpart + (size_t)kc * CS + (size_t)bb * NQ * FQ;
    #pragma unroll
    for (int mi = 0; mi < 2; ++mi) {
        float is[4];
        #pragma unroll
        for (int r = 0; r < 4; ++r)
            is[r] = isq[(size_t)bb * NQ + row0 + mi * 16 + g * 4 + r] * (1.0f / HSS);
        #pragma unroll
        for (int ct = 0; ct < 8; ++ct)
            #pragma unroll
            for (int r = 0; r < 4; ++r)
                hp[(size_t)(row0 + mi * 16 + g * 4 + r) * FQ + ct * 16 + c] = f2bf(acc[mi][ct][r] * is[r]);
    }
}

// ---- Kernel 5: out = (sum_kc hpart(bf16) + x) @ W ----
template<int KC>
__global__ __launch_bounds__(256) void k_out4(const unsigned short* __restrict__ hp,
                                              const float* __restrict__ x,
                                              const float* __restrict__ W,
                                              float* __restrict__ out) {
    const size_t CS = (size_t)BQ * NQ * FQ;
    __shared__ float hx[8][128];
    int r0 = blockIdx.x * 8;
    int tid = threadIdx.x;
    #pragma unroll
    for (int it = 0; it < 4; ++it) {
        int idx = tid + it * 256;
        int ri = idx >> 7, f = idx & 127;
        size_t gi = (size_t)(r0 + ri) * FQ + f;
        float s = x[gi];
        #pragma unroll
        for (int k = 0; k < KC; ++k) s += bf2f(hp[k * CS + gi]);
        hx[ri][f] = s;
    }
    __syncthreads();
    int o = tid & 127, half = tid >> 7;
    float acc[4] = {0.f, 0.f, 0.f, 0.f};
    for (int f = 0; f < 128; ++f) {
        float wv = W[f * 128 + o];
        #pragma unroll
        for (int j = 0; j < 4; ++j)
            acc[j] += hx[half * 4 + j][f] * wv;
    }
    #pragma unroll
    for (int j = 0; j < 4; ++j)
        out[(size_t)(r0 + half * 4 + j) * FQ + o] = acc[j];
}

template<int KC>
static void run_all(const float* x, const float* W, float* out,
                    unsigned char* adjF, unsigned short* xnF, unsigned char* hsF,
                    float* dpart, float* isq, unsigned short* h, unsigned short* hpart,
                    hipStream_t stream) {
    const float ts[3] = {0.05f, 0.1f, 0.15f};
    for (int i = 0; i < 3; ++i) {
        if (i == 0) k_rownorm<<<BQ * NQ / 16, 256, 0, stream>>>(x, xnF);
        else        k_rownorm4<KC><<<BQ * NQ / 16, 256, 0, stream>>>(hpart, h, xnF);
        k_adj<<<BQ * 256, 512, 0, stream>>>(xnF, adjF, dpart, ts[i]);
        if (i == 0) k_prep_f32 <<<BQ * NQ / 32, 256, 0, stream>>>(x, dpart, isq, hsF);
        else        k_prep_bf16<<<BQ * NQ / 32, 256, 0, stream>>>(h, dpart, isq, hsF);
        k_gemm2<KC><<<BQ * 16 * KC, 256, 0, stream>>>(adjF, hsF, isq, hpart);
    }
    k_out4<KC><<<BQ * NQ / 8, 256, 0, stream>>>(hpart, x, W, out);
}

extern "C" void kernel_launch(void* const* d_in, const int* in_sizes, int n_in,
                              void* d_out, int out_size, void* d_ws, size_t ws_size,
                              hipStream_t stream) {
    const float* x = (const float*)d_in[0];
    const float* W = (const float*)d_in[1];
    float* out = (float*)d_out;
    char* ws = (char*)d_ws;

    const size_t CS   = (size_t)BQ * NQ * FQ;
    const size_t oADJ = 0;
    const size_t oXN  = oADJ + (size_t)BQ * NQ * NQ;          // 32 MiB fp8 adj
    const size_t oHST = oXN  + CS * 2;                        // +4 MiB bf16 xn
    const size_t oD   = oHST + CS;                            // +2 MiB fp8 hs
    const size_t oISQ = oD   + (size_t)16 * BQ * NQ * 4;      // +1 MiB
    const size_t oH   = oISQ + (size_t)BQ * NQ * 4;           // +64 KiB
    const size_t oHP  = oH   + CS * 2;                        // +4 MiB bf16 h
    const size_t need1 = oHP + 1 * CS * 2;
    const size_t need2 = oHP + 2 * CS * 2;
    const size_t need4 = oHP + 4 * CS * 2;

    unsigned char*  adjF = (unsigned char*)(ws + oADJ);
    unsigned short* xnF  = (unsigned short*)(ws + oXN);
    unsigned char*  hsF  = (unsigned char*)(ws + oHST);
    float* dpart = (float*)(ws + oD);
    float* isq   = (float*)(ws + oISQ);
    unsigned short* h     = (unsigned short*)(ws + oH);
    unsigned short* hpart = (unsigned short*)(ws + oHP);

    if (ws_size >= need4)
        run_all<4>(x, W, out, adjF, xnF, hsF, dpart, isq, h, hpart, stream);
    else if (ws_size >= need2)
        run_all<2>(x, W, out, adjF, xnF, hsF, dpart, isq, h, hpart, stream);
    else if (ws_size >= need1)
        run_all<1>(x, W, out, adjF, xnF, hsF, dpart, isq, h, hpart, stream);
    // else: workspace too small (diagnostic — output stays poisoned)
}

// Round 16
// 149.458 us; speedup vs baseline: 1.2001x; 1.0220x over previous
//
#include <hip/hip_runtime.h>
#include <hip/hip_bf16.h>
#include <cstdint>

#define BQ 8
#define NQ 2048
#define FQ 128
#define NG (NQ * 16)            // adjF n-group stride in BYTES (fp8)
#define HSS 256.0f              // hs fp8 scale

typedef __attribute__((ext_vector_type(8))) short short8;
typedef __attribute__((ext_vector_type(4))) float f32x4;
typedef __attribute__((ext_vector_type(8))) unsigned short us8;
typedef __attribute__((ext_vector_type(2))) unsigned int u32x2;

__device__ __forceinline__ unsigned short f2bf(float f) {
    union { float f; unsigned int u; } c; c.f = f;
    unsigned int u = c.u;
    u = (u + 0x7FFFu + ((u >> 16) & 1u)) >> 16;   // RNE
    return (unsigned short)u;
}
__device__ __forceinline__ float bf2f(unsigned short u) {
    union { unsigned int i; float f; } c; c.i = (unsigned int)u << 16; return c.f;
}
// pack 2 f32 -> 2 e4m3 bytes into low / high word half
__device__ __forceinline__ unsigned int pk8lo(float a, float b, unsigned int old) {
    return (unsigned int)__builtin_amdgcn_cvt_pk_fp8_f32(a, b, (int)old, false);
}
__device__ __forceinline__ unsigned int pk8hi(float a, float b, unsigned int old) {
    return (unsigned int)__builtin_amdgcn_cvt_pk_fp8_f32(a, b, (int)old, true);
}

// Layouts (per batch):
//   xnF : bf16 [n/16][k/8][n%16][k%8]  elem addr = (n>>4)*2048 + (k>>3)*128 + (n&15)*8 + (k&7)
//   adjF: fp8  [n/16][m/8][n%16][m%8]  BYTE addr = (n>>4)*NG + (m>>3)*128 + (n&15)*8 + (m&7)
//   hsF : fp8  [m/8][f][m%8]           BYTE addr = (m>>3)*1024 + f*8 + (m&7); value = hs*HSS
// hpart, h: bf16 row-major [n][f].
// r16: k_adj stages A-rows + B-cols in LDS (64 KB) via global_load_lds — kills the
// ~400 MB/iter L2 operand re-read (the real k_adj bottleneck, r15 post-mortem).

// ---- Kernel 1a: row L2-normalize x -> xnF (16 rows/block) ----
__global__ __launch_bounds__(256) void k_rownorm(const float* __restrict__ h,
                                                 unsigned short* __restrict__ xnF) {
    int t = threadIdx.x;
    int rl = t >> 4, j = t & 15;
    size_t row = (size_t)blockIdx.x * 16 + rl;
    const float* hr = h + row * FQ + j * 8;
    float v[8];
    #pragma unroll
    for (int e = 0; e < 8; ++e) v[e] = hr[e];
    float s = 0.f;
    #pragma unroll
    for (int e = 0; e < 8; ++e) s += v[e] * v[e];
    s += __shfl_xor(s, 1, 64);
    s += __shfl_xor(s, 2, 64);
    s += __shfl_xor(s, 4, 64);
    s += __shfl_xor(s, 8, 64);
    float inv = 1.0f / fmaxf(sqrtf(s), 1e-8f);
    us8 u;
    #pragma unroll
    for (int e = 0; e < 8; ++e) u[e] = f2bf(v[e] * inv);
    *(us8*)(xnF + (size_t)blockIdx.x * 2048 + j * 128 + rl * 8) = u;
}

// ---- Kernel 1b: reduce bf16 K-split partials -> bf16 h, normalize -> xnF ----
template<int KC>
__global__ __launch_bounds__(256) void k_rownorm4(const unsigned short* __restrict__ hp,
                                                  unsigned short* __restrict__ hout,
                                                  unsigned short* __restrict__ xnF) {
    const size_t CS = (size_t)BQ * NQ * FQ;
    int t = threadIdx.x;
    int rl = t >> 4, j = t & 15;
    size_t row = (size_t)blockIdx.x * 16 + rl;
    size_t o = row * FQ + j * 8;
    float v[8] = {0.f, 0.f, 0.f, 0.f, 0.f, 0.f, 0.f, 0.f};
    #pragma unroll
    for (int k = 0; k < KC; ++k) {
        us8 pv = *(const us8*)(hp + k * CS + o);
        #pragma unroll
        for (int e = 0; e < 8; ++e) v[e] += bf2f(pv[e]);
    }
    us8 hw;
    #pragma unroll
    for (int e = 0; e < 8; ++e) hw[e] = f2bf(v[e]);
    *(us8*)(hout + o) = hw;
    float s = 0.f;
    #pragma unroll
    for (int e = 0; e < 8; ++e) s += v[e] * v[e];
    s += __shfl_xor(s, 1, 64);
    s += __shfl_xor(s, 2, 64);
    s += __shfl_xor(s, 4, 64);
    s += __shfl_xor(s, 8, 64);
    float inv = 1.0f / fmaxf(sqrtf(s), 1e-8f);
    us8 u;
    #pragma unroll
    for (int e = 0; e < 8; ++e) u[e] = f2bf(v[e] * inv);
    *(us8*)(xnF + (size_t)blockIdx.x * 2048 + j * 128 + rl * 8) = u;
}

// ---- Kernel 2: S = xn@xn^T (bf16 MFMA), threshold f32, transposed fp8 store,
//      dpart sums. 128x128 tile per 512-thr block, XCD-swizzled.
//      r16: A-rows (32 KB) + B-cols (32 KB) staged in LDS via global_load_lds. ----
__global__ __launch_bounds__(512) void k_adj(const unsigned short* __restrict__ xnF,
                                             unsigned char* __restrict__ adjF,
                                             float* __restrict__ dpart, float t) {
    __shared__ unsigned short As[16384];       // 32 KB: rows I*128..+127 (8 n-groups)
    __shared__ unsigned short Bsh[16384];      // 32 KB: cols J*128..+127

    int bid = blockIdx.x;
    int blk = (bid & 7) * (int)(gridDim.x >> 3) + (bid >> 3);   // XCD swizzle
    int bb  = blk >> 8;
    int ij  = blk & 255;
    int I   = ij >> 4, J = ij & 15;
    int tid = threadIdx.x;
    int wid = tid >> 6, lane = tid & 63;
    int wr = wid >> 1, wc = wid & 1;
    int g = lane >> 4, c = lane & 15;

    const unsigned short* xb = xnF + (size_t)bb * NQ * FQ;
    int rowb = I * 128 + wr * 32;
    int colb = J * 128 + wc * 64;

    // stage A and B panels (each 16384 elems = 32 KB, contiguous in xnF layout)
    {
        const unsigned short* srcA = xb + (size_t)(I * 8) * 2048;
        const unsigned short* srcB = xb + (size_t)(J * 8) * 2048;
        #pragma unroll
        for (int it = 0; it < 4; ++it) {
            __builtin_amdgcn_global_load_lds(
                (const __attribute__((address_space(1))) void*)(srcA + (size_t)(it * 512 + tid) * 8),
                (__attribute__((address_space(3))) void*)(As + (it * 512 + wid * 64) * 8),
                16, 0, 0);
            __builtin_amdgcn_global_load_lds(
                (const __attribute__((address_space(1))) void*)(srcB + (size_t)(it * 512 + tid) * 8),
                (__attribute__((address_space(3))) void*)(Bsh + (it * 512 + wid * 64) * 8),
                16, 0, 0);
        }
    }
    __syncthreads();    // drains vmcnt before barrier

    short8 a[2][4];
    #pragma unroll
    for (int mi = 0; mi < 2; ++mi)
        #pragma unroll
        for (int ks = 0; ks < 4; ++ks)
            a[mi][ks] = *(const short8*)(As + (wr * 2 + mi) * 2048 + (ks * 4 + g) * 128 + c * 8);

    f32x4 acc[2][4];
    #pragma unroll
    for (int mi = 0; mi < 2; ++mi)
        #pragma unroll
        for (int ni = 0; ni < 4; ++ni) acc[mi][ni] = (f32x4){0.f, 0.f, 0.f, 0.f};

    #pragma unroll
    for (int ni = 0; ni < 4; ++ni) {
        short8 b[4];
        #pragma unroll
        for (int ks = 0; ks < 4; ++ks)
            b[ks] = *(const short8*)(Bsh + (wc * 4 + ni) * 2048 + (ks * 4 + g) * 128 + c * 8);
        #pragma unroll
        for (int mi = 0; mi < 2; ++mi)
            #pragma unroll
            for (int ks = 0; ks < 4; ++ks)
                acc[mi][ni] = __builtin_amdgcn_mfma_f32_16x16x32_bf16(a[mi][ks], b[ks], acc[mi][ni], 0, 0, 0);
    }

    unsigned char* adjb = adjF + (size_t)bb * NQ * NQ;   // 1 B/elem
    __shared__ float dsm[2][128];
    float dl[2][4];
    #pragma unroll
    for (int mi = 0; mi < 2; ++mi)
        #pragma unroll
        for (int r = 0; r < 4; ++r) dl[mi][r] = 0.f;

    #pragma unroll
    for (int mi = 0; mi < 2; ++mi)
        #pragma unroll
        for (int ni = 0; ni < 4; ++ni) {
            f32x4 v = acc[mi][ni];
            float x0 = (v[0] > t) ? v[0] : 0.0f;   // strict threshold in f32
            float x1 = (v[1] > t) ? v[1] : 0.0f;
            float x2 = (v[2] > t) ? v[2] : 0.0f;
            float x3 = (v[3] > t) ? v[3] : 0.0f;
            dl[mi][0] += x0; dl[mi][1] += x1; dl[mi][2] += x2; dl[mi][3] += x3;
            unsigned int u = pk8lo(x0, x1, 0u);
            u = pk8hi(x2, x3, u);
            // mirror-transposed (S symmetric): element (row, col) stored at (n=col, m=row)
            *(unsigned int*)(adjb + (size_t)((colb >> 4) + ni) * NG
                                  + (size_t)((rowb >> 3) + mi * 2 + (g >> 1)) * 128
                                  + c * 8 + (g & 1) * 4) = u;
        }

    #pragma unroll
    for (int mi = 0; mi < 2; ++mi)
        #pragma unroll
        for (int r = 0; r < 4; ++r) {
            float s = dl[mi][r];
            s += __shfl_xor(s, 1, 64);
            s += __shfl_xor(s, 2, 64);
            s += __shfl_xor(s, 4, 64);
            s += __shfl_xor(s, 8, 64);
            dl[mi][r] = s;
        }
    if (c == 0) {
        #pragma unroll
        for (int mi = 0; mi < 2; ++mi)
            #pragma unroll
            for (int r = 0; r < 4; ++r)
                dsm[wc][wr * 32 + mi * 16 + g * 4 + r] = dl[mi][r];
    }
    __syncthreads();
    if (tid < 128)
        dpart[((size_t)J * 8 + bb) * NQ + I * 128 + tid] = dsm[0][tid] + dsm[1][tid];
}

// ---- Kernel 3a (iter 0): isq from dpart; hsF (fp8, xHSS) from f32 x ----
__global__ __launch_bounds__(256) void k_prep_f32(const float* __restrict__ h,
                                                  const float* __restrict__ dpart,
                                                  float* __restrict__ isq,
                                                  unsigned char* __restrict__ hsF) {
    __shared__ float tile[32][129];
    __shared__ float iv[32];
    int r0 = blockIdx.x * 32;
    int bb = r0 >> 11;
    int m0 = r0 & (NQ - 1);
    int tid = threadIdx.x;
    if (tid < 32) {
        float s = 0.f;
        #pragma unroll
        for (int j = 0; j < 16; ++j)
            s += dpart[((size_t)j * 8 + bb) * NQ + m0 + tid];
        float v = 1.0f / sqrtf(s);
        iv[tid] = v;
        isq[r0 + tid] = v;
    }
    #pragma unroll
    for (int it = 0; it < 16; ++it) {
        int idx = tid + it * 256;
        int mi = idx >> 7, f = idx & 127;
        tile[mi][f] = h[(size_t)(r0 + mi) * FQ + f];
    }
    __syncthreads();
    unsigned char* hb = hsF + (size_t)bb * NQ * FQ;
    #pragma unroll
    for (int it = 0; it < 2; ++it) {
        int p = tid + it * 256;
        int f = p & 127, mc = p >> 7;
        float sv[8];
        #pragma unroll
        for (int e = 0; e < 8; ++e)
            sv[e] = tile[mc * 8 + e][f] * iv[mc * 8 + e] * HSS;
        u32x2 u;
        u[0] = pk8hi(sv[2], sv[3], pk8lo(sv[0], sv[1], 0u));
        u[1] = pk8hi(sv[6], sv[7], pk8lo(sv[4], sv[5], 0u));
        *(u32x2*)(hb + (size_t)((m0 >> 3) + mc) * 1024 + f * 8) = u;
    }
}

// ---- Kernel 3b (iters 1,2): isq from dpart; hsF (fp8) from bf16 h ----
__global__ __launch_bounds__(256) void k_prep_bf16(const unsigned short* __restrict__ h,
                                                   const float* __restrict__ dpart,
                                                   float* __restrict__ isq,
                                                   unsigned char* __restrict__ hsF) {
    __shared__ float tile[32][129];
    __shared__ float iv[32];
    int r0 = blockIdx.x * 32;
    int bb = r0 >> 11;
    int m0 = r0 & (NQ - 1);
    int tid = threadIdx.x;
    if (tid < 32) {
        float s = 0.f;
        #pragma unroll
        for (int j = 0; j < 16; ++j)
            s += dpart[((size_t)j * 8 + bb) * NQ + m0 + tid];
        float v = 1.0f / sqrtf(s);
        iv[tid] = v;
        isq[r0 + tid] = v;
    }
    #pragma unroll
    for (int it = 0; it < 16; ++it) {
        int idx = tid + it * 256;
        int mi = idx >> 7, f = idx & 127;
        tile[mi][f] = bf2f(h[(size_t)(r0 + mi) * FQ + f]);
    }
    __syncthreads();
    unsigned char* hb = hsF + (size_t)bb * NQ * FQ;
    #pragma unroll
    for (int it = 0; it < 2; ++it) {
        int p = tid + it * 256;
        int f = p & 127, mc = p >> 7;
        float sv[8];
        #pragma unroll
        for (int e = 0; e < 8; ++e)
            sv[e] = tile[mc * 8 + e][f] * iv[mc * 8 + e] * HSS;
        u32x2 u;
        u[0] = pk8hi(sv[2], sv[3], pk8lo(sv[0], sv[1], 0u));
        u[1] = pk8hi(sv[6], sv[7], pk8lo(sv[4], sv[5], 0u));
        *(u32x2*)(hb + (size_t)((m0 >> 3) + mc) * 1024 + f * 8) = u;
    }
}

// ---- Kernel 4: hpart[kc](bf16) = isq/HSS * (adjF_fp8 @ hsF_fp8), fp8 MFMA.
//      LDS-staged B (32 KB phases via global_load_lds), 32-row waves, 128 rows/blk. ----
template<int KC>
__global__ __launch_bounds__(256) void k_gemm2(const unsigned char* __restrict__ adjF,
                                               const unsigned char* __restrict__ hsF,
                                               const float* __restrict__ isq,
                                               unsigned short* __restrict__ hpart) {
    constexpr int KE = NQ / KC;
    constexpr int KS = KE / 32;
    constexpr int PH = 8;              // 32 KB LDS phase (PH*4 m-groups x 1024 B)
    const size_t CS = (size_t)BQ * NQ * FQ;
    __shared__ unsigned char Bs[PH * 4 * 1024];

    int bid = blockIdx.x;
    int lb = (bid & 7) * (int)(gridDim.x >> 3) + (bid >> 3);   // XCD swizzle
    int kc = lb % KC;
    int rt = (lb / KC) & 15;
    int bb = lb / (KC * 16);
    int wid = threadIdx.x >> 6, lane = threadIdx.x & 63;
    int g = lane >> 4, c = lane & 15;
    int row0 = rt * 128 + wid * 32;

    const unsigned char* adjr = adjF + (size_t)bb * NQ * NQ + (size_t)(row0 >> 4) * NG
                                     + (size_t)((kc * KE) >> 3) * 128;
    const unsigned char* hb   = hsF + (size_t)bb * NQ * FQ + (size_t)((kc * KE) >> 3) * 1024;

    f32x4 acc[2][8];
    #pragma unroll
    for (int mi = 0; mi < 2; ++mi)
        #pragma unroll
        for (int i = 0; i < 8; ++i) acc[mi][i] = (f32x4){0.f, 0.f, 0.f, 0.f};

    for (int ph = 0; ph < KS / PH; ++ph) {
        __syncthreads();     // previous phase's readers done before overwrite
        {
            const unsigned char* src = hb + (size_t)ph * (PH * 4 * 1024);
            #pragma unroll
            for (int it = 0; it < 8; ++it) {
                __builtin_amdgcn_global_load_lds(
                    (const __attribute__((address_space(1))) void*)(src + (size_t)(it * 256 + threadIdx.x) * 16),
                    (__attribute__((address_space(3))) void*)(Bs + (it * 256 + wid * 64) * 16),
                    16, 0, 0);
            }
        }
        __syncthreads();     // compiler drains vmcnt before barrier
        #pragma unroll
        for (int k2 = 0; k2 < PH; ++k2) {
            int kk = ph * PH + k2;
            long a0 = *(const long*)(adjr + (size_t)(kk * 4 + g) * 128 + c * 8);
            long a1 = *(const long*)(adjr + NG + (size_t)(kk * 4 + g) * 128 + c * 8);
            #pragma unroll
            for (int ct = 0; ct < 8; ++ct) {
                long bfr = *(const long*)(Bs + (k2 * 4 + g) * 1024 + (ct * 16 + c) * 8);
                acc[0][ct] = __builtin_amdgcn_mfma_f32_16x16x32_fp8_fp8(a0, bfr, acc[0][ct], 0, 0, 0);
                acc[1][ct] = __builtin_amdgcn_mfma_f32_16x16x32_fp8_fp8(a1, bfr, acc[1][ct], 0, 0, 0);
            }
        }
    }

    unsigned short* hp = hpart + (size_t)kc * CS + (size_t)bb * NQ * FQ;
    #pragma unroll
    for (int mi = 0; mi < 2; ++mi) {
        float is[4];
        #pragma unroll
        for (int r = 0; r < 4; ++r)
            is[r] = isq[(size_t)bb * NQ + row0 + mi * 16 + g * 4 + r] * (1.0f / HSS);
        #pragma unroll
        for (int ct = 0; ct < 8; ++ct)
            #pragma unroll
            for (int r = 0; r < 4; ++r)
                hp[(size_t)(row0 + mi * 16 + g * 4 + r) * FQ + ct * 16 + c] = f2bf(acc[mi][ct][r] * is[r]);
    }
}

// ---- Kernel 5: out = (sum_kc hpart(bf16) + x) @ W ----
template<int KC>
__global__ __launch_bounds__(256) void k_out4(const unsigned short* __restrict__ hp,
                                              const float* __restrict__ x,
                                              const float* __restrict__ W,
                                              float* __restrict__ out) {
    const size_t CS = (size_t)BQ * NQ * FQ;
    __shared__ float hx[8][128];
    int r0 = blockIdx.x * 8;
    int tid = threadIdx.x;
    #pragma unroll
    for (int it = 0; it < 4; ++it) {
        int idx = tid + it * 256;
        int ri = idx >> 7, f = idx & 127;
        size_t gi = (size_t)(r0 + ri) * FQ + f;
        float s = x[gi];
        #pragma unroll
        for (int k = 0; k < KC; ++k) s += bf2f(hp[k * CS + gi]);
        hx[ri][f] = s;
    }
    __syncthreads();
    int o = tid & 127, half = tid >> 7;
    float acc[4] = {0.f, 0.f, 0.f, 0.f};
    for (int f = 0; f < 128; ++f) {
        float wv = W[f * 128 + o];
        #pragma unroll
        for (int j = 0; j < 4; ++j)
            acc[j] += hx[half * 4 + j][f] * wv;
    }
    #pragma unroll
    for (int j = 0; j < 4; ++j)
        out[(size_t)(r0 + half * 4 + j) * FQ + o] = acc[j];
}

template<int KC>
static void run_all(const float* x, const float* W, float* out,
                    unsigned char* adjF, unsigned short* xnF, unsigned char* hsF,
                    float* dpart, float* isq, unsigned short* h, unsigned short* hpart,
                    hipStream_t stream) {
    const float ts[3] = {0.05f, 0.1f, 0.15f};
    for (int i = 0; i < 3; ++i) {
        if (i == 0) k_rownorm<<<BQ * NQ / 16, 256, 0, stream>>>(x, xnF);
        else        k_rownorm4<KC><<<BQ * NQ / 16, 256, 0, stream>>>(hpart, h, xnF);
        k_adj<<<BQ * 256, 512, 0, stream>>>(xnF, adjF, dpart, ts[i]);
        if (i == 0) k_prep_f32 <<<BQ * NQ / 32, 256, 0, stream>>>(x, dpart, isq, hsF);
        else        k_prep_bf16<<<BQ * NQ / 32, 256, 0, stream>>>(h, dpart, isq, hsF);
        k_gemm2<KC><<<BQ * 16 * KC, 256, 0, stream>>>(adjF, hsF, isq, hpart);
    }
    k_out4<KC><<<BQ * NQ / 8, 256, 0, stream>>>(hpart, x, W, out);
}

extern "C" void kernel_launch(void* const* d_in, const int* in_sizes, int n_in,
                              void* d_out, int out_size, void* d_ws, size_t ws_size,
                              hipStream_t stream) {
    const float* x = (const float*)d_in[0];
    const float* W = (const float*)d_in[1];
    float* out = (float*)d_out;
    char* ws = (char*)d_ws;

    const size_t CS   = (size_t)BQ * NQ * FQ;
    const size_t oADJ = 0;
    const size_t oXN  = oADJ + (size_t)BQ * NQ * NQ;          // 32 MiB fp8 adj
    const size_t oHST = oXN  + CS * 2;                        // +4 MiB bf16 xn
    const size_t oD   = oHST + CS;                            // +2 MiB fp8 hs
    const size_t oISQ = oD   + (size_t)16 * BQ * NQ * 4;      // +1 MiB
    const size_t oH   = oISQ + (size_t)BQ * NQ * 4;           // +64 KiB
    const size_t oHP  = oH   + CS * 2;                        // +4 MiB bf16 h
    const size_t need1 = oHP + 1 * CS * 2;
    const size_t need2 = oHP + 2 * CS * 2;
    const size_t need4 = oHP + 4 * CS * 2;

    unsigned char*  adjF = (unsigned char*)(ws + oADJ);
    unsigned short* xnF  = (unsigned short*)(ws + oXN);
    unsigned char*  hsF  = (unsigned char*)(ws + oHST);
    float* dpart = (float*)(ws + oD);
    float* isq   = (float*)(ws + oISQ);
    unsigned short* h     = (unsigned short*)(ws + oH);
    unsigned short* hpart = (unsigned short*)(ws + oHP);

    if (ws_size >= need4)
        run_all<4>(x, W, out, adjF, xnF, hsF, dpart, isq, h, hpart, stream);
    else if (ws_size >= need2)
        run_all<2>(x, W, out, adjF, xnF, hsF, dpart, isq, h, hpart, stream);
    else if (ws_size >= need1)
        run_all<1>(x, W, out, adjF, xnF, hsF, dpart, isq, h, hpart, stream);
    // else: workspace too small (diagnostic — output stays poisoned)
}

// Round 17
// 146.217 us; speedup vs baseline: 1.2267x; 1.0222x over previous
//
#include <hip/hip_runtime.h>
#include <hip/hip_bf16.h>
#include <cstdint>

#define BQ 8
#define NQ 2048
#define FQ 128
#define NG (NQ * 16)            // adjF n-group stride in BYTES (fp8)
#define HSS 256.0f              // hs fp8 scale

typedef __attribute__((ext_vector_type(8))) short short8;
typedef __attribute__((ext_vector_type(4))) float f32x4;
typedef __attribute__((ext_vector_type(8))) unsigned short us8;
typedef __attribute__((ext_vector_type(2))) unsigned int u32x2;

__device__ __forceinline__ unsigned short f2bf(float f) {
    union { float f; unsigned int u; } c; c.f = f;
    unsigned int u = c.u;
    u = (u + 0x7FFFu + ((u >> 16) & 1u)) >> 16;   // RNE
    return (unsigned short)u;
}
__device__ __forceinline__ float bf2f(unsigned short u) {
    union { unsigned int i; float f; } c; c.i = (unsigned int)u << 16; return c.f;
}
__device__ __forceinline__ unsigned int pk8lo(float a, float b, unsigned int old) {
    return (unsigned int)__builtin_amdgcn_cvt_pk_fp8_f32(a, b, (int)old, false);
}
__device__ __forceinline__ unsigned int pk8hi(float a, float b, unsigned int old) {
    return (unsigned int)__builtin_amdgcn_cvt_pk_fp8_f32(a, b, (int)old, true);
}

// Layouts (per batch):
//   xnF : bf16 [n/16][k/8][n%16][k%8]  elem addr = (n>>4)*2048 + (k>>3)*128 + (n&15)*8 + (k&7)
//   adjF: fp8  [n/16][m/8][n%16][m%8]  BYTE addr = (n>>4)*NG + (m>>3)*128 + (n&15)*8 + (m&7)
//   hsF : fp8  [m/8][f][m%8]           BYTE addr = (m>>3)*1024 + f*8 + (m&7); value = hs*HSS
// h buffers: bf16 row-major [b][n][f].
// r17: k_gemm3 = gemm2 + rownorm4 fused (in-block K-split + LDS reduce + in-block
// row-norm) -> hpart round-trip (32 MiB/iter) and 2 dispatches/iter deleted.

// ---- Kernel 1: row L2-normalize x (f32) -> xnF (16 rows/block), iter 0 only ----
__global__ __launch_bounds__(256) void k_rownorm(const float* __restrict__ h,
                                                 unsigned short* __restrict__ xnF) {
    int t = threadIdx.x;
    int rl = t >> 4, j = t & 15;
    size_t row = (size_t)blockIdx.x * 16 + rl;
    const float* hr = h + row * FQ + j * 8;
    float v[8];
    #pragma unroll
    for (int e = 0; e < 8; ++e) v[e] = hr[e];
    float s = 0.f;
    #pragma unroll
    for (int e = 0; e < 8; ++e) s += v[e] * v[e];
    s += __shfl_xor(s, 1, 64);
    s += __shfl_xor(s, 2, 64);
    s += __shfl_xor(s, 4, 64);
    s += __shfl_xor(s, 8, 64);
    float inv = 1.0f / fmaxf(sqrtf(s), 1e-8f);
    us8 u;
    #pragma unroll
    for (int e = 0; e < 8; ++e) u[e] = f2bf(v[e] * inv);
    *(us8*)(xnF + (size_t)blockIdx.x * 2048 + j * 128 + rl * 8) = u;
}

// ---- Kernel 2 (r16 form): S = xn@xn^T, threshold, transposed fp8 store, dpart.
//      128x128 tile / 512-thr block, XCD-swizzled, LDS-staged panels. ----
__global__ __launch_bounds__(512) void k_adj(const unsigned short* __restrict__ xnF,
                                             unsigned char* __restrict__ adjF,
                                             float* __restrict__ dpart, float t) {
    __shared__ unsigned short As[16384];
    __shared__ unsigned short Bsh[16384];

    int bid = blockIdx.x;
    int blk = (bid & 7) * (int)(gridDim.x >> 3) + (bid >> 3);   // XCD swizzle
    int bb  = blk >> 8;
    int ij  = blk & 255;
    int I   = ij >> 4, J = ij & 15;
    int tid = threadIdx.x;
    int wid = tid >> 6, lane = tid & 63;
    int wr = wid >> 1, wc = wid & 1;
    int g = lane >> 4, c = lane & 15;

    const unsigned short* xb = xnF + (size_t)bb * NQ * FQ;
    int rowb = I * 128 + wr * 32;
    int colb = J * 128 + wc * 64;

    {
        const unsigned short* srcA = xb + (size_t)(I * 8) * 2048;
        const unsigned short* srcB = xb + (size_t)(J * 8) * 2048;
        #pragma unroll
        for (int it = 0; it < 4; ++it) {
            __builtin_amdgcn_global_load_lds(
                (const __attribute__((address_space(1))) void*)(srcA + (size_t)(it * 512 + tid) * 8),
                (__attribute__((address_space(3))) void*)(As + (it * 512 + wid * 64) * 8),
                16, 0, 0);
            __builtin_amdgcn_global_load_lds(
                (const __attribute__((address_space(1))) void*)(srcB + (size_t)(it * 512 + tid) * 8),
                (__attribute__((address_space(3))) void*)(Bsh + (it * 512 + wid * 64) * 8),
                16, 0, 0);
        }
    }
    __syncthreads();

    short8 a[2][4];
    #pragma unroll
    for (int mi = 0; mi < 2; ++mi)
        #pragma unroll
        for (int ks = 0; ks < 4; ++ks)
            a[mi][ks] = *(const short8*)(As + (wr * 2 + mi) * 2048 + (ks * 4 + g) * 128 + c * 8);

    f32x4 acc[2][4];
    #pragma unroll
    for (int mi = 0; mi < 2; ++mi)
        #pragma unroll
        for (int ni = 0; ni < 4; ++ni) acc[mi][ni] = (f32x4){0.f, 0.f, 0.f, 0.f};

    #pragma unroll
    for (int ni = 0; ni < 4; ++ni) {
        short8 b[4];
        #pragma unroll
        for (int ks = 0; ks < 4; ++ks)
            b[ks] = *(const short8*)(Bsh + (wc * 4 + ni) * 2048 + (ks * 4 + g) * 128 + c * 8);
        #pragma unroll
        for (int mi = 0; mi < 2; ++mi)
            #pragma unroll
            for (int ks = 0; ks < 4; ++ks)
                acc[mi][ni] = __builtin_amdgcn_mfma_f32_16x16x32_bf16(a[mi][ks], b[ks], acc[mi][ni], 0, 0, 0);
    }

    unsigned char* adjb = adjF + (size_t)bb * NQ * NQ;
    __shared__ float dsm[2][128];
    float dl[2][4];
    #pragma unroll
    for (int mi = 0; mi < 2; ++mi)
        #pragma unroll
        for (int r = 0; r < 4; ++r) dl[mi][r] = 0.f;

    #pragma unroll
    for (int mi = 0; mi < 2; ++mi)
        #pragma unroll
        for (int ni = 0; ni < 4; ++ni) {
            f32x4 v = acc[mi][ni];
            float x0 = (v[0] > t) ? v[0] : 0.0f;   // strict threshold in f32
            float x1 = (v[1] > t) ? v[1] : 0.0f;
            float x2 = (v[2] > t) ? v[2] : 0.0f;
            float x3 = (v[3] > t) ? v[3] : 0.0f;
            dl[mi][0] += x0; dl[mi][1] += x1; dl[mi][2] += x2; dl[mi][3] += x3;
            unsigned int u = pk8lo(x0, x1, 0u);
            u = pk8hi(x2, x3, u);
            *(unsigned int*)(adjb + (size_t)((colb >> 4) + ni) * NG
                                  + (size_t)((rowb >> 3) + mi * 2 + (g >> 1)) * 128
                                  + c * 8 + (g & 1) * 4) = u;
        }

    #pragma unroll
    for (int mi = 0; mi < 2; ++mi)
        #pragma unroll
        for (int r = 0; r < 4; ++r) {
            float s = dl[mi][r];
            s += __shfl_xor(s, 1, 64);
            s += __shfl_xor(s, 2, 64);
            s += __shfl_xor(s, 4, 64);
            s += __shfl_xor(s, 8, 64);
            dl[mi][r] = s;
        }
    if (c == 0) {
        #pragma unroll
        for (int mi = 0; mi < 2; ++mi)
            #pragma unroll
            for (int r = 0; r < 4; ++r)
                dsm[wc][wr * 32 + mi * 16 + g * 4 + r] = dl[mi][r];
    }
    __syncthreads();
    if (tid < 128)
        dpart[((size_t)J * 8 + bb) * NQ + I * 128 + tid] = dsm[0][tid] + dsm[1][tid];
}

// ---- Kernel 3a (iter 0): isq from dpart; hsF (fp8, xHSS) from f32 x ----
__global__ __launch_bounds__(256) void k_prep_f32(const float* __restrict__ h,
                                                  const float* __restrict__ dpart,
                                                  float* __restrict__ isq,
                                                  unsigned char* __restrict__ hsF) {
    __shared__ float tile[32][129];
    __shared__ float iv[32];
    int r0 = blockIdx.x * 32;
    int bb = r0 >> 11;
    int m0 = r0 & (NQ - 1);
    int tid = threadIdx.x;
    if (tid < 32) {
        float s = 0.f;
        #pragma unroll
        for (int j = 0; j < 16; ++j)
            s += dpart[((size_t)j * 8 + bb) * NQ + m0 + tid];
        float v = 1.0f / sqrtf(s);
        iv[tid] = v;
        isq[r0 + tid] = v;
    }
    #pragma unroll
    for (int it = 0; it < 16; ++it) {
        int idx = tid + it * 256;
        int mi = idx >> 7, f = idx & 127;
        tile[mi][f] = h[(size_t)(r0 + mi) * FQ + f];
    }
    __syncthreads();
    unsigned char* hb = hsF + (size_t)bb * NQ * FQ;
    #pragma unroll
    for (int it = 0; it < 2; ++it) {
        int p = tid + it * 256;
        int f = p & 127, mc = p >> 7;
        float sv[8];
        #pragma unroll
        for (int e = 0; e < 8; ++e)
            sv[e] = tile[mc * 8 + e][f] * iv[mc * 8 + e] * HSS;
        u32x2 u;
        u[0] = pk8hi(sv[2], sv[3], pk8lo(sv[0], sv[1], 0u));
        u[1] = pk8hi(sv[6], sv[7], pk8lo(sv[4], sv[5], 0u));
        *(u32x2*)(hb + (size_t)((m0 >> 3) + mc) * 1024 + f * 8) = u;
    }
}

// ---- Kernel 3b (iters 1,2): isq from dpart; hsF (fp8) from bf16 h ----
__global__ __launch_bounds__(256) void k_prep_bf16(const unsigned short* __restrict__ h,
                                                   const float* __restrict__ dpart,
                                                   float* __restrict__ isq,
                                                   unsigned char* __restrict__ hsF) {
    __shared__ float tile[32][129];
    __shared__ float iv[32];
    int r0 = blockIdx.x * 32;
    int bb = r0 >> 11;
    int m0 = r0 & (NQ - 1);
    int tid = threadIdx.x;
    if (tid < 32) {
        float s = 0.f;
        #pragma unroll
        for (int j = 0; j < 16; ++j)
            s += dpart[((size_t)j * 8 + bb) * NQ + m0 + tid];
        float v = 1.0f / sqrtf(s);
        iv[tid] = v;
        isq[r0 + tid] = v;
    }
    #pragma unroll
    for (int it = 0; it < 16; ++it) {
        int idx = tid + it * 256;
        int mi = idx >> 7, f = idx & 127;
        tile[mi][f] = bf2f(h[(size_t)(r0 + mi) * FQ + f]);
    }
    __syncthreads();
    unsigned char* hb = hsF + (size_t)bb * NQ * FQ;
    #pragma unroll
    for (int it = 0; it < 2; ++it) {
        int p = tid + it * 256;
        int f = p & 127, mc = p >> 7;
        float sv[8];
        #pragma unroll
        for (int e = 0; e < 8; ++e)
            sv[e] = tile[mc * 8 + e][f] * iv[mc * 8 + e] * HSS;
        u32x2 u;
        u[0] = pk8hi(sv[2], sv[3], pk8lo(sv[0], sv[1], 0u));
        u[1] = pk8hi(sv[6], sv[7], pk8lo(sv[4], sv[5], 0u));
        *(u32x2*)(hb + (size_t)((m0 >> 3) + mc) * 1024 + f * 8) = u;
    }
}

// ---- Kernel 4 (r17): h_out = isq*(adjF_fp8 @ hsF_fp8)/HSS, + in-block row-norm
//      -> writes h (bf16) and next-iter xnF directly. 64-row blocks, 512 thr,
//      8 waves = 2 row-halves (rg) x 4 K-quarters (kh). Grid 256, XCD-swizzled. ----
template<bool LAST>
__global__ __launch_bounds__(512) void k_gemm3(const unsigned char* __restrict__ adjF,
                                               const unsigned char* __restrict__ hsF,
                                               const float* __restrict__ isq,
                                               unsigned short* __restrict__ hout,
                                               unsigned short* __restrict__ xnF) {
    __shared__ unsigned char Bs[32768];        // 4 kh regions x 8 KB phase slice
    __shared__ float red[64][128];             // 32 KB f32 partial-sum buffer

    int bid = blockIdx.x;
    int lb = (bid & 7) * 32 + (bid >> 3);      // XCD swizzle (grid 256)
    int bb = lb >> 5;
    int rt = lb & 31;
    int row0g = rt * 64;
    int tid = threadIdx.x;
    int wid = tid >> 6, lane = tid & 63;
    int g = lane >> 4, c = lane & 15;
    int rg = wid >> 2, kh = wid & 3;
    int wrow = row0g + rg * 32;

    const unsigned char* adjr = adjF + (size_t)bb * NQ * NQ + (size_t)(wrow >> 4) * NG;
    const unsigned char* hb   = hsF + (size_t)bb * NQ * FQ;

    f32x4 acc[2][8];
    #pragma unroll
    for (int mi = 0; mi < 2; ++mi)
        #pragma unroll
        for (int i = 0; i < 8; ++i) acc[mi][i] = (f32x4){0.f, 0.f, 0.f, 0.f};

    int khr = wid >> 1;            // staging region this wave fills (2 waves/region)
    int wlo = wid & 1;

    for (int ph = 0; ph < 8; ++ph) {
        __syncthreads();           // previous phase's readers done
        {
            const unsigned char* src = hb + (size_t)(khr * 64 + ph * 8) * 1024 + wlo * 1024;
            unsigned char* dst = Bs + khr * 8192 + wlo * 1024;
            #pragma unroll
            for (int it = 0; it < 4; ++it) {
                __builtin_amdgcn_global_load_lds(
                    (const __attribute__((address_space(1))) void*)(src + it * 2048 + lane * 16),
                    (__attribute__((address_space(3))) void*)(dst + it * 2048),
                    16, 0, 0);
            }
        }
        __syncthreads();           // drains vmcnt
        #pragma unroll
        for (int kk2 = 0; kk2 < 2; ++kk2) {
            int mstep = kh * 16 + ph * 2 + kk2;     // global 32-elem K step
            long a0 = *(const long*)(adjr + (size_t)(mstep * 4 + g) * 128 + c * 8);
            long a1 = *(const long*)(adjr + NG + (size_t)(mstep * 4 + g) * 128 + c * 8);
            #pragma unroll
            for (int ct = 0; ct < 8; ++ct) {
                long bfr = *(const long*)(Bs + kh * 8192 + kk2 * 4096 + g * 1024 + (ct * 16 + c) * 8);
                acc[0][ct] = __builtin_amdgcn_mfma_f32_16x16x32_fp8_fp8(a0, bfr, acc[0][ct], 0, 0, 0);
                acc[1][ct] = __builtin_amdgcn_mfma_f32_16x16x32_fp8_fp8(a1, bfr, acc[1][ct], 0, 0, 0);
            }
        }
    }

    // cross-kh reduction into red (barrier-ordered, deterministic)
    __syncthreads();
    #pragma unroll
    for (int s = 0; s < 4; ++s) {
        if (kh == s) {
            #pragma unroll
            for (int mi = 0; mi < 2; ++mi)
                #pragma unroll
                for (int ct = 0; ct < 8; ++ct)
                    #pragma unroll
                    for (int r = 0; r < 4; ++r) {
                        int rl = rg * 32 + mi * 16 + g * 4 + r;
                        if (s == 0) red[rl][ct * 16 + c] = acc[mi][ct][r];
                        else        red[rl][ct * 16 + c] += acc[mi][ct][r];
                    }
        }
        __syncthreads();
    }

    // final pass: scale, row-norm, write h bf16 (+ xnF fragments unless LAST)
    int rl = tid >> 3;             // 0..63
    int j  = tid & 7;              // 8 f-chunks of 16
    int n  = row0g + rl;
    float scale = isq[(size_t)bb * NQ + n] * (1.0f / HSS);
    float v[16];
    float s = 0.f;
    #pragma unroll
    for (int e = 0; e < 16; ++e) {
        float x = red[rl][j * 16 + e] * scale;
        v[e] = x;
        s += x * x;
    }
    s += __shfl_xor(s, 1, 64);
    s += __shfl_xor(s, 2, 64);
    s += __shfl_xor(s, 4, 64);
    float inv = 1.0f / fmaxf(sqrtf(s), 1e-8f);

    us8 h0, h1;
    #pragma unroll
    for (int e = 0; e < 8; ++e) { h0[e] = f2bf(v[e]); h1[e] = f2bf(v[8 + e]); }
    unsigned short* hrow = hout + ((size_t)bb * NQ + n) * FQ + j * 16;
    *(us8*)hrow = h0;
    *(us8*)(hrow + 8) = h1;

    if constexpr (!LAST) {
        us8 u0, u1;
        #pragma unroll
        for (int e = 0; e < 8; ++e) { u0[e] = f2bf(v[e] * inv); u1[e] = f2bf(v[8 + e] * inv); }
        unsigned short* xd = xnF + (size_t)bb * NQ * FQ + (size_t)(n >> 4) * 2048
                                 + (j * 2) * 128 + (n & 15) * 8;
        *(us8*)xd = u0;
        *(us8*)(xd + 128) = u1;
    }
}

// ---- Kernel 5: out = (h3(bf16) + x) @ W ----
__global__ __launch_bounds__(256) void k_out(const unsigned short* __restrict__ h3,
                                             const float* __restrict__ x,
                                             const float* __restrict__ W,
                                             float* __restrict__ out) {
    __shared__ float hx[8][128];
    int r0 = blockIdx.x * 8;
    int tid = threadIdx.x;
    #pragma unroll
    for (int it = 0; it < 4; ++it) {
        int idx = tid + it * 256;
        int ri = idx >> 7, f = idx & 127;
        size_t gi = (size_t)(r0 + ri) * FQ + f;
        hx[ri][f] = bf2f(h3[gi]) + x[gi];
    }
    __syncthreads();
    int o = tid & 127, half = tid >> 7;
    float acc[4] = {0.f, 0.f, 0.f, 0.f};
    for (int f = 0; f < 128; ++f) {
        float wv = W[f * 128 + o];
        #pragma unroll
        for (int j = 0; j < 4; ++j)
            acc[j] += hx[half * 4 + j][f] * wv;
    }
    #pragma unroll
    for (int j = 0; j < 4; ++j)
        out[(size_t)(r0 + half * 4 + j) * FQ + o] = acc[j];
}

extern "C" void kernel_launch(void* const* d_in, const int* in_sizes, int n_in,
                              void* d_out, int out_size, void* d_ws, size_t ws_size,
                              hipStream_t stream) {
    const float* x = (const float*)d_in[0];
    const float* W = (const float*)d_in[1];
    float* out = (float*)d_out;
    char* ws = (char*)d_ws;

    const size_t CS   = (size_t)BQ * NQ * FQ;
    const size_t oADJ = 0;
    const size_t oXN  = oADJ + (size_t)BQ * NQ * NQ;          // 32 MiB fp8 adj
    const size_t oHST = oXN  + CS * 2;                        // +4 MiB bf16 xn
    const size_t oD   = oHST + CS;                            // +2 MiB fp8 hs
    const size_t oISQ = oD   + (size_t)16 * BQ * NQ * 4;      // +1 MiB
    const size_t oHA  = oISQ + (size_t)BQ * NQ * 4;           // +64 KiB
    const size_t oHB  = oHA  + CS * 2;                        // +4 MiB bf16 hA
    const size_t need = oHB  + CS * 2;                        // +4 MiB bf16 hB
    if (ws_size < need) return;   // diagnostic: output stays poisoned

    unsigned char*  adjF = (unsigned char*)(ws + oADJ);
    unsigned short* xnF  = (unsigned short*)(ws + oXN);
    unsigned char*  hsF  = (unsigned char*)(ws + oHST);
    float* dpart = (float*)(ws + oD);
    float* isq   = (float*)(ws + oISQ);
    unsigned short* hA = (unsigned short*)(ws + oHA);
    unsigned short* hB = (unsigned short*)(ws + oHB);

    const float ts[3] = {0.05f, 0.1f, 0.15f};

    // iter 0
    k_rownorm<<<BQ * NQ / 16, 256, 0, stream>>>(x, xnF);
    k_adj<<<BQ * 256, 512, 0, stream>>>(xnF, adjF, dpart, ts[0]);
    k_prep_f32<<<BQ * NQ / 32, 256, 0, stream>>>(x, dpart, isq, hsF);
    k_gemm3<false><<<BQ * 32, 512, 0, stream>>>(adjF, hsF, isq, hA, xnF);
    // iter 1
    k_adj<<<BQ * 256, 512, 0, stream>>>(xnF, adjF, dpart, ts[1]);
    k_prep_bf16<<<BQ * NQ / 32, 256, 0, stream>>>(hA, dpart, isq, hsF);
    k_gemm3<false><<<BQ * 32, 512, 0, stream>>>(adjF, hsF, isq, hB, xnF);
    // iter 2
    k_adj<<<BQ * 256, 512, 0, stream>>>(xnF, adjF, dpart, ts[2]);
    k_prep_bf16<<<BQ * NQ / 32, 256, 0, stream>>>(hB, dpart, isq, hsF);
    k_gemm3<true><<<BQ * 32, 512, 0, stream>>>(adjF, hsF, isq, hA, xnF);

    k_out<<<BQ * NQ / 8, 256, 0, stream>>>(hA, x, W, out);
}

// Round 18
// 141.584 us; speedup vs baseline: 1.2668x; 1.0327x over previous
//
#include <hip/hip_runtime.h>
#include <hip/hip_bf16.h>
#include <cstdint>

#define BQ 8
#define NQ 2048
#define FQ 128
#define NG (NQ * 16)            // adjF n-group stride in BYTES (fp8)
#define HSS 256.0f              // hs fp8 scale

typedef __attribute__((ext_vector_type(8))) short short8;
typedef __attribute__((ext_vector_type(4))) float f32x4;
typedef __attribute__((ext_vector_type(8))) unsigned short us8;
typedef __attribute__((ext_vector_type(2))) unsigned int u32x2;
typedef __attribute__((ext_vector_type(4))) unsigned int u32x4;

__device__ __forceinline__ unsigned short f2bf(float f) {
    union { float f; unsigned int u; } c; c.f = f;
    unsigned int u = c.u;
    u = (u + 0x7FFFu + ((u >> 16) & 1u)) >> 16;   // RNE
    return (unsigned short)u;
}
__device__ __forceinline__ float bf2f(unsigned short u) {
    union { unsigned int i; float f; } c; c.i = (unsigned int)u << 16; return c.f;
}
__device__ __forceinline__ unsigned int pk8lo(float a, float b, unsigned int old) {
    return (unsigned int)__builtin_amdgcn_cvt_pk_fp8_f32(a, b, (int)old, false);
}
__device__ __forceinline__ unsigned int pk8hi(float a, float b, unsigned int old) {
    return (unsigned int)__builtin_amdgcn_cvt_pk_fp8_f32(a, b, (int)old, true);
}

// Layouts (per batch):
//   xnF : bf16 [n/16][k/8][n%16][k%8]  elem addr = (n>>4)*2048 + (k>>3)*128 + (n&15)*8 + (k&7)
//   adjF: fp8  [n/16][m/8][n%16][m%8]  BYTE addr = (n>>4)*NG + (m>>3)*128 + (n&15)*8 + (m&7)
//   hsF : fp8  [m/8][f][m%8]           BYTE addr = (m>>3)*1024 + f*8 + (m&7); value = hs*HSS
// h buffers: bf16 row-major [b][n][f].
// r18: TRIANGLE k_adj — only I<=J tiles computed (136 blocks/batch vs 256);
// each tile stored twice (mirror-transposed direct + direct via LDS bounce with
// in-register 4x8 byte transpose); dpart slot (I) for J-rows from column sums.

// ---- Kernel 1: row L2-normalize x (f32) -> xnF (16 rows/block), iter 0 only ----
__global__ __launch_bounds__(256) void k_rownorm(const float* __restrict__ h,
                                                 unsigned short* __restrict__ xnF) {
    int t = threadIdx.x;
    int rl = t >> 4, j = t & 15;
    size_t row = (size_t)blockIdx.x * 16 + rl;
    const float* hr = h + row * FQ + j * 8;
    float v[8];
    #pragma unroll
    for (int e = 0; e < 8; ++e) v[e] = hr[e];
    float s = 0.f;
    #pragma unroll
    for (int e = 0; e < 8; ++e) s += v[e] * v[e];
    s += __shfl_xor(s, 1, 64);
    s += __shfl_xor(s, 2, 64);
    s += __shfl_xor(s, 4, 64);
    s += __shfl_xor(s, 8, 64);
    float inv = 1.0f / fmaxf(sqrtf(s), 1e-8f);
    us8 u;
    #pragma unroll
    for (int e = 0; e < 8; ++e) u[e] = f2bf(v[e] * inv);
    *(us8*)(xnF + (size_t)blockIdx.x * 2048 + j * 128 + rl * 8) = u;
}

// ---- Kernel 2 (r18): triangle S-tiles. Grid = 8 batches x 136 (I<=J) pairs. ----
__global__ __launch_bounds__(512) void k_adj(const unsigned short* __restrict__ xnF,
                                             unsigned char* __restrict__ adjF,
                                             float* __restrict__ dpart, float t) {
    __shared__ unsigned short As[16384];                 // 32 KB: I panel
    __shared__ union { unsigned short Bsh[16384];        // 32 KB: J panel ...
                       unsigned char  T2[128 * 132]; } ub;  // ... reused as bounce
    __shared__ float dsm[2][128];
    __shared__ float csm[2][128];

    int bid = blockIdx.x;
    int bb = bid & 7;                       // batch -> XCD locality
    int pr = bid >> 3;                      // pair index 0..135
    int I = 0;
    { int p = pr; while (p >= 16 - I) { p -= 16 - I; ++I; } pr = p; }
    int J = I + pr;

    int tid = threadIdx.x;
    int wid = tid >> 6, lane = tid & 63;
    int wr = wid >> 1, wc = wid & 1;        // 4 row-quarters x 2 col-halves
    int g = lane >> 4, c = lane & 15;

    const unsigned short* xb = xnF + (size_t)bb * NQ * FQ;
    int rowb = I * 128 + wr * 32;
    int colb = J * 128 + wc * 64;

    {   // stage panels (32 KB each, contiguous in xnF fragment layout)
        const unsigned short* srcA = xb + (size_t)(I * 8) * 2048;
        const unsigned short* srcB = xb + (size_t)(J * 8) * 2048;
        #pragma unroll
        for (int it = 0; it < 4; ++it) {
            __builtin_amdgcn_global_load_lds(
                (const __attribute__((address_space(1))) void*)(srcA + (size_t)(it * 512 + tid) * 8),
                (__attribute__((address_space(3))) void*)(As + (it * 512 + wid * 64) * 8),
                16, 0, 0);
            __builtin_amdgcn_global_load_lds(
                (const __attribute__((address_space(1))) void*)(srcB + (size_t)(it * 512 + tid) * 8),
                (__attribute__((address_space(3))) void*)(ub.Bsh + (it * 512 + wid * 64) * 8),
                16, 0, 0);
        }
    }
    __syncthreads();

    short8 a[2][4];
    #pragma unroll
    for (int mi = 0; mi < 2; ++mi)
        #pragma unroll
        for (int ks = 0; ks < 4; ++ks)
            a[mi][ks] = *(const short8*)(As + (wr * 2 + mi) * 2048 + (ks * 4 + g) * 128 + c * 8);

    f32x4 acc[2][4];
    #pragma unroll
    for (int mi = 0; mi < 2; ++mi)
        #pragma unroll
        for (int ni = 0; ni < 4; ++ni) acc[mi][ni] = (f32x4){0.f, 0.f, 0.f, 0.f};

    #pragma unroll
    for (int ni = 0; ni < 4; ++ni) {
        short8 b[4];
        #pragma unroll
        for (int ks = 0; ks < 4; ++ks)
            b[ks] = *(const short8*)(ub.Bsh + (wc * 4 + ni) * 2048 + (ks * 4 + g) * 128 + c * 8);
        #pragma unroll
        for (int mi = 0; mi < 2; ++mi)
            #pragma unroll
            for (int ks = 0; ks < 4; ++ks)
                acc[mi][ni] = __builtin_amdgcn_mfma_f32_16x16x32_bf16(a[mi][ks], b[ks], acc[mi][ni], 0, 0, 0);
    }

    __syncthreads();    // all Bsh reads done before T2 overlay writes

    unsigned char* adjb = adjF + (size_t)bb * NQ * NQ;
    float dl[2][4];
    float csl[4] = {0.f, 0.f, 0.f, 0.f};
    #pragma unroll
    for (int mi = 0; mi < 2; ++mi)
        #pragma unroll
        for (int r = 0; r < 4; ++r) dl[mi][r] = 0.f;

    #pragma unroll
    for (int mi = 0; mi < 2; ++mi)
        #pragma unroll
        for (int ni = 0; ni < 4; ++ni) {
            f32x4 v = acc[mi][ni];
            float x0 = (v[0] > t) ? v[0] : 0.0f;   // strict threshold in f32
            float x1 = (v[1] > t) ? v[1] : 0.0f;
            float x2 = (v[2] > t) ? v[2] : 0.0f;
            float x3 = (v[3] > t) ? v[3] : 0.0f;
            dl[mi][0] += x0; dl[mi][1] += x1; dl[mi][2] += x2; dl[mi][3] += x3;
            csl[ni] += x0 + x1 + x2 + x3;          // col partial (rows of this lane)
            unsigned int u = pk8lo(x0, x1, 0u);
            u = pk8hi(x2, x3, u);
            // store 1: mirror-transposed (n = col in J-range, m = row in I-range)
            *(unsigned int*)(adjb + (size_t)((colb >> 4) + ni) * NG
                                  + (size_t)((rowb >> 3) + mi * 2 + (g >> 1)) * 128
                                  + c * 8 + (g & 1) * 4) = u;
            // bounce for store 2 (skip on diagonal): T2[colL][rowL], stride 132
            if (I != J) {
                int colL = wc * 64 + ni * 16 + c;
                int rowL = wr * 32 + mi * 16 + g * 4;
                *(unsigned int*)(ub.T2 + colL * 132 + rowL) = u;
            }
        }

    // row sums -> dsm (reduce over c-lanes)
    #pragma unroll
    for (int mi = 0; mi < 2; ++mi)
        #pragma unroll
        for (int r = 0; r < 4; ++r) {
            float s = dl[mi][r];
            s += __shfl_xor(s, 1, 64);
            s += __shfl_xor(s, 2, 64);
            s += __shfl_xor(s, 4, 64);
            s += __shfl_xor(s, 8, 64);
            dl[mi][r] = s;
        }
    if (c == 0) {
        #pragma unroll
        for (int mi = 0; mi < 2; ++mi)
            #pragma unroll
            for (int r = 0; r < 4; ++r)
                dsm[wc][wr * 32 + mi * 16 + g * 4 + r] = dl[mi][r];
    }
    // col sums -> csm (reduce over g-lanes)
    if (I != J) {
        #pragma unroll
        for (int ni = 0; ni < 4; ++ni) {
            float s = csl[ni];
            s += __shfl_xor(s, 16, 64);
            s += __shfl_xor(s, 32, 64);
            csl[ni] = s;
        }
        if (lane < 16) {
            #pragma unroll
            for (int ni = 0; ni < 4; ++ni)
                csm[wr & 1][wc * 64 + ni * 16 + lane] = csl[ni];
        }
        // csm must combine all 4 wr quarters -> two-step: wr0/1 write, wr2/3 add
        // (ordering via the barrier below + second pass)
    }
    __syncthreads();
    if (I != J && (wr >= 2) && lane < 16) {
        #pragma unroll
        for (int ni = 0; ni < 4; ++ni)
            csm[wr & 1][wc * 64 + ni * 16 + lane] += csl[ni];
    }
    __syncthreads();

    // dpart writes
    if (tid < 128)
        dpart[((size_t)J * 8 + bb) * NQ + I * 128 + tid] = dsm[0][tid] + dsm[1][tid];
    if (I != J) {
        if (tid < 128)
            dpart[((size_t)I * 8 + bb) * NQ + J * 128 + tid] = csm[0][tid] + csm[1][tid];
        // store 2: direct orientation (n = row in I-range, m = col in J-range)
        int ng = wid;                 // 0..7 n-group within I-range
        int mg = lane >> 2;           // 0..15 m-group within J-range
        int part = lane & 3;          // n%16 quarter
        unsigned int w[8];
        #pragma unroll
        for (int ml = 0; ml < 8; ++ml)
            w[ml] = *(const unsigned int*)(ub.T2 + (mg * 8 + ml) * 132 + ng * 16 + part * 4);
        unsigned int o32[8];
        #pragma unroll
        for (int i = 0; i < 4; ++i)
            #pragma unroll
            for (int h = 0; h < 2; ++h)
                o32[i * 2 + h] = ((w[h * 4 + 0] >> (8 * i)) & 0xFFu)
                               | (((w[h * 4 + 1] >> (8 * i)) & 0xFFu) << 8)
                               | (((w[h * 4 + 2] >> (8 * i)) & 0xFFu) << 16)
                               | (((w[h * 4 + 3] >> (8 * i)) & 0xFFu) << 24);
        unsigned char* dst = adjb + (size_t)(I * 8 + ng) * NG + (size_t)(J * 16 + mg) * 128 + part * 32;
        *(u32x4*)dst        = (u32x4){o32[0], o32[1], o32[2], o32[3]};
        *(u32x4*)(dst + 16) = (u32x4){o32[4], o32[5], o32[6], o32[7]};
    }
}

// ---- Kernel 3a (iter 0): isq from dpart; hsF (fp8, xHSS) from f32 x ----
__global__ __launch_bounds__(256) void k_prep_f32(const float* __restrict__ h,
                                                  const float* __restrict__ dpart,
                                                  float* __restrict__ isq,
                                                  unsigned char* __restrict__ hsF) {
    __shared__ float tile[32][129];
    __shared__ float iv[32];
    int r0 = blockIdx.x * 32;
    int bb = r0 >> 11;
    int m0 = r0 & (NQ - 1);
    int tid = threadIdx.x;
    if (tid < 32) {
        float s = 0.f;
        #pragma unroll
        for (int j = 0; j < 16; ++j)
            s += dpart[((size_t)j * 8 + bb) * NQ + m0 + tid];
        float v = 1.0f / sqrtf(s);
        iv[tid] = v;
        isq[r0 + tid] = v;
    }
    #pragma unroll
    for (int it = 0; it < 16; ++it) {
        int idx = tid + it * 256;
        int mi = idx >> 7, f = idx & 127;
        tile[mi][f] = h[(size_t)(r0 + mi) * FQ + f];
    }
    __syncthreads();
    unsigned char* hb = hsF + (size_t)bb * NQ * FQ;
    #pragma unroll
    for (int it = 0; it < 2; ++it) {
        int p = tid + it * 256;
        int f = p & 127, mc = p >> 7;
        float sv[8];
        #pragma unroll
        for (int e = 0; e < 8; ++e)
            sv[e] = tile[mc * 8 + e][f] * iv[mc * 8 + e] * HSS;
        u32x2 u;
        u[0] = pk8hi(sv[2], sv[3], pk8lo(sv[0], sv[1], 0u));
        u[1] = pk8hi(sv[6], sv[7], pk8lo(sv[4], sv[5], 0u));
        *(u32x2*)(hb + (size_t)((m0 >> 3) + mc) * 1024 + f * 8) = u;
    }
}

// ---- Kernel 3b (iters 1,2): isq from dpart; hsF (fp8) from bf16 h ----
__global__ __launch_bounds__(256) void k_prep_bf16(const unsigned short* __restrict__ h,
                                                   const float* __restrict__ dpart,
                                                   float* __restrict__ isq,
                                                   unsigned char* __restrict__ hsF) {
    __shared__ float tile[32][129];
    __shared__ float iv[32];
    int r0 = blockIdx.x * 32;
    int bb = r0 >> 11;
    int m0 = r0 & (NQ - 1);
    int tid = threadIdx.x;
    if (tid < 32) {
        float s = 0.f;
        #pragma unroll
        for (int j = 0; j < 16; ++j)
            s += dpart[((size_t)j * 8 + bb) * NQ + m0 + tid];
        float v = 1.0f / sqrtf(s);
        iv[tid] = v;
        isq[r0 + tid] = v;
    }
    #pragma unroll
    for (int it = 0; it < 16; ++it) {
        int idx = tid + it * 256;
        int mi = idx >> 7, f = idx & 127;
        tile[mi][f] = bf2f(h[(size_t)(r0 + mi) * FQ + f]);
    }
    __syncthreads();
    unsigned char* hb = hsF + (size_t)bb * NQ * FQ;
    #pragma unroll
    for (int it = 0; it < 2; ++it) {
        int p = tid + it * 256;
        int f = p & 127, mc = p >> 7;
        float sv[8];
        #pragma unroll
        for (int e = 0; e < 8; ++e)
            sv[e] = tile[mc * 8 + e][f] * iv[mc * 8 + e] * HSS;
        u32x2 u;
        u[0] = pk8hi(sv[2], sv[3], pk8lo(sv[0], sv[1], 0u));
        u[1] = pk8hi(sv[6], sv[7], pk8lo(sv[4], sv[5], 0u));
        *(u32x2*)(hb + (size_t)((m0 >> 3) + mc) * 1024 + f * 8) = u;
    }
}

// ---- Kernel 4 (r17): h_out = isq*(adjF_fp8 @ hsF_fp8)/HSS + in-block row-norm ----
template<bool LAST>
__global__ __launch_bounds__(512) void k_gemm3(const unsigned char* __restrict__ adjF,
                                               const unsigned char* __restrict__ hsF,
                                               const float* __restrict__ isq,
                                               unsigned short* __restrict__ hout,
                                               unsigned short* __restrict__ xnF) {
    __shared__ unsigned char Bs[32768];
    __shared__ float red[64][128];

    int bid = blockIdx.x;
    int lb = (bid & 7) * 32 + (bid >> 3);
    int bb = lb >> 5;
    int rt = lb & 31;
    int row0g = rt * 64;
    int tid = threadIdx.x;
    int wid = tid >> 6, lane = tid & 63;
    int g = lane >> 4, c = lane & 15;
    int rg = wid >> 2, kh = wid & 3;
    int wrow = row0g + rg * 32;

    const unsigned char* adjr = adjF + (size_t)bb * NQ * NQ + (size_t)(wrow >> 4) * NG;
    const unsigned char* hb   = hsF + (size_t)bb * NQ * FQ;

    f32x4 acc[2][8];
    #pragma unroll
    for (int mi = 0; mi < 2; ++mi)
        #pragma unroll
        for (int i = 0; i < 8; ++i) acc[mi][i] = (f32x4){0.f, 0.f, 0.f, 0.f};

    int khr = wid >> 1;
    int wlo = wid & 1;

    for (int ph = 0; ph < 8; ++ph) {
        __syncthreads();
        {
            const unsigned char* src = hb + (size_t)(khr * 64 + ph * 8) * 1024 + wlo * 1024;
            unsigned char* dst = Bs + khr * 8192 + wlo * 1024;
            #pragma unroll
            for (int it = 0; it < 4; ++it) {
                __builtin_amdgcn_global_load_lds(
                    (const __attribute__((address_space(1))) void*)(src + it * 2048 + lane * 16),
                    (__attribute__((address_space(3))) void*)(dst + it * 2048),
                    16, 0, 0);
            }
        }
        __syncthreads();
        #pragma unroll
        for (int kk2 = 0; kk2 < 2; ++kk2) {
            int mstep = kh * 16 + ph * 2 + kk2;
            long a0 = *(const long*)(adjr + (size_t)(mstep * 4 + g) * 128 + c * 8);
            long a1 = *(const long*)(adjr + NG + (size_t)(mstep * 4 + g) * 128 + c * 8);
            #pragma unroll
            for (int ct = 0; ct < 8; ++ct) {
                long bfr = *(const long*)(Bs + kh * 8192 + kk2 * 4096 + g * 1024 + (ct * 16 + c) * 8);
                acc[0][ct] = __builtin_amdgcn_mfma_f32_16x16x32_fp8_fp8(a0, bfr, acc[0][ct], 0, 0, 0);
                acc[1][ct] = __builtin_amdgcn_mfma_f32_16x16x32_fp8_fp8(a1, bfr, acc[1][ct], 0, 0, 0);
            }
        }
    }

    __syncthreads();
    #pragma unroll
    for (int s = 0; s < 4; ++s) {
        if (kh == s) {
            #pragma unroll
            for (int mi = 0; mi < 2; ++mi)
                #pragma unroll
                for (int ct = 0; ct < 8; ++ct)
                    #pragma unroll
                    for (int r = 0; r < 4; ++r) {
                        int rl = rg * 32 + mi * 16 + g * 4 + r;
                        if (s == 0) red[rl][ct * 16 + c] = acc[mi][ct][r];
                        else        red[rl][ct * 16 + c] += acc[mi][ct][r];
                    }
        }
        __syncthreads();
    }

    int rl = tid >> 3;
    int j  = tid & 7;
    int n  = row0g + rl;
    float scale = isq[(size_t)bb * NQ + n] * (1.0f / HSS);
    float v[16];
    float s = 0.f;
    #pragma unroll
    for (int e = 0; e < 16; ++e) {
        float x = red[rl][j * 16 + e] * scale;
        v[e] = x;
        s += x * x;
    }
    s += __shfl_xor(s, 1, 64);
    s += __shfl_xor(s, 2, 64);
    s += __shfl_xor(s, 4, 64);
    float inv = 1.0f / fmaxf(sqrtf(s), 1e-8f);

    us8 h0, h1;
    #pragma unroll
    for (int e = 0; e < 8; ++e) { h0[e] = f2bf(v[e]); h1[e] = f2bf(v[8 + e]); }
    unsigned short* hrow = hout + ((size_t)bb * NQ + n) * FQ + j * 16;
    *(us8*)hrow = h0;
    *(us8*)(hrow + 8) = h1;

    if constexpr (!LAST) {
        us8 u0, u1;
        #pragma unroll
        for (int e = 0; e < 8; ++e) { u0[e] = f2bf(v[e] * inv); u1[e] = f2bf(v[8 + e] * inv); }
        unsigned short* xd = xnF + (size_t)bb * NQ * FQ + (size_t)(n >> 4) * 2048
                                 + (j * 2) * 128 + (n & 15) * 8;
        *(us8*)xd = u0;
        *(us8*)(xd + 128) = u1;
    }
}

// ---- Kernel 5: out = (h3(bf16) + x) @ W ----
__global__ __launch_bounds__(256) void k_out(const unsigned short* __restrict__ h3,
                                             const float* __restrict__ x,
                                             const float* __restrict__ W,
                                             float* __restrict__ out) {
    __shared__ float hx[8][128];
    int r0 = blockIdx.x * 8;
    int tid = threadIdx.x;
    #pragma unroll
    for (int it = 0; it < 4; ++it) {
        int idx = tid + it * 256;
        int ri = idx >> 7, f = idx & 127;
        size_t gi = (size_t)(r0 + ri) * FQ + f;
        hx[ri][f] = bf2f(h3[gi]) + x[gi];
    }
    __syncthreads();
    int o = tid & 127, half = tid >> 7;
    float acc[4] = {0.f, 0.f, 0.f, 0.f};
    for (int f = 0; f < 128; ++f) {
        float wv = W[f * 128 + o];
        #pragma unroll
        for (int j = 0; j < 4; ++j)
            acc[j] += hx[half * 4 + j][f] * wv;
    }
    #pragma unroll
    for (int j = 0; j < 4; ++j)
        out[(size_t)(r0 + half * 4 + j) * FQ + o] = acc[j];
}

extern "C" void kernel_launch(void* const* d_in, const int* in_sizes, int n_in,
                              void* d_out, int out_size, void* d_ws, size_t ws_size,
                              hipStream_t stream) {
    const float* x = (const float*)d_in[0];
    const float* W = (const float*)d_in[1];
    float* out = (float*)d_out;
    char* ws = (char*)d_ws;

    const size_t CS   = (size_t)BQ * NQ * FQ;
    const size_t oADJ = 0;
    const size_t oXN  = oADJ + (size_t)BQ * NQ * NQ;          // 32 MiB fp8 adj
    const size_t oHST = oXN  + CS * 2;                        // +4 MiB bf16 xn
    const size_t oD   = oHST + CS;                            // +2 MiB fp8 hs
    const size_t oISQ = oD   + (size_t)16 * BQ * NQ * 4;      // +1 MiB
    const size_t oHA  = oISQ + (size_t)BQ * NQ * 4;           // +64 KiB
    const size_t oHB  = oHA  + CS * 2;                        // +4 MiB bf16 hA
    const size_t need = oHB  + CS * 2;                        // +4 MiB bf16 hB
    if (ws_size < need) return;   // diagnostic: output stays poisoned

    unsigned char*  adjF = (unsigned char*)(ws + oADJ);
    unsigned short* xnF  = (unsigned short*)(ws + oXN);
    unsigned char*  hsF  = (unsigned char*)(ws + oHST);
    float* dpart = (float*)(ws + oD);
    float* isq   = (float*)(ws + oISQ);
    unsigned short* hA = (unsigned short*)(ws + oHA);
    unsigned short* hB = (unsigned short*)(ws + oHB);

    const float ts[3] = {0.05f, 0.1f, 0.15f};

    // iter 0
    k_rownorm<<<BQ * NQ / 16, 256, 0, stream>>>(x, xnF);
    k_adj<<<BQ * 136, 512, 0, stream>>>(xnF, adjF, dpart, ts[0]);
    k_prep_f32<<<BQ * NQ / 32, 256, 0, stream>>>(x, dpart, isq, hsF);
    k_gemm3<false><<<BQ * 32, 512, 0, stream>>>(adjF, hsF, isq, hA, xnF);
    // iter 1
    k_adj<<<BQ * 136, 512, 0, stream>>>(xnF, adjF, dpart, ts[1]);
    k_prep_bf16<<<BQ * NQ / 32, 256, 0, stream>>>(hA, dpart, isq, hsF);
    k_gemm3<false><<<BQ * 32, 512, 0, stream>>>(adjF, hsF, isq, hB, xnF);
    // iter 2
    k_adj<<<BQ * 136, 512, 0, stream>>>(xnF, adjF, dpart, ts[2]);
    k_prep_bf16<<<BQ * NQ / 32, 256, 0, stream>>>(hB, dpart, isq, hsF);
    k_gemm3<true><<<BQ * 32, 512, 0, stream>>>(adjF, hsF, isq, hA, xnF);

    k_out<<<BQ * NQ / 8, 256, 0, stream>>>(hA, x, W, out);
}

// Round 19
// 133.459 us; speedup vs baseline: 1.3439x; 1.0609x over previous
//
#include <hip/hip_runtime.h>
#include <hip/hip_bf16.h>
#include <cstdint>

#define BQ 8
#define NQ 2048
#define FQ 128
#define NG (NQ * 16)            // adjF n-group stride in BYTES (fp8)
#define HSS 256.0f              // hs fp8 scale

typedef __attribute__((ext_vector_type(8))) short short8;
typedef __attribute__((ext_vector_type(4))) float f32x4;
typedef __attribute__((ext_vector_type(8))) unsigned short us8;
typedef __attribute__((ext_vector_type(2))) unsigned int u32x2;
typedef __attribute__((ext_vector_type(4))) unsigned int u32x4;

__device__ __forceinline__ unsigned short f2bf(float f) {
    union { float f; unsigned int u; } c; c.f = f;
    unsigned int u = c.u;
    u = (u + 0x7FFFu + ((u >> 16) & 1u)) >> 16;   // RNE
    return (unsigned short)u;
}
__device__ __forceinline__ float bf2f(unsigned short u) {
    union { unsigned int i; float f; } c; c.i = (unsigned int)u << 16; return c.f;
}
__device__ __forceinline__ unsigned int pk8lo(float a, float b, unsigned int old) {
    return (unsigned int)__builtin_amdgcn_cvt_pk_fp8_f32(a, b, (int)old, false);
}
__device__ __forceinline__ unsigned int pk8hi(float a, float b, unsigned int old) {
    return (unsigned int)__builtin_amdgcn_cvt_pk_fp8_f32(a, b, (int)old, true);
}

// Layouts (per batch):
//   xnF : bf16 [n/16][k/8][n%16][k%8]  elem addr = (n>>4)*2048 + (k>>3)*128 + (n&15)*8 + (k&7)
//   adjF: fp8  [n/16][m/8][n%16][m%8]  BYTE addr = (n>>4)*NG + (m>>3)*128 + (n&15)*8 + (m&7)
//   hsF : fp8  [m/8][f][m%8]           BYTE addr = (m>>3)*1024 + f*8 + (m&7); value = hs*HSS
// h buffers: bf16 row-major [b][n][f].
// r19: k_gemm3 -> 32-row blocks, grid 512 = 2 blocks/CU (second block's compute
// covers the first's staging barriers; 1 block/CU had zero cross-block overlap).

// ---- Kernel 1: row L2-normalize x (f32) -> xnF (16 rows/block), iter 0 only ----
__global__ __launch_bounds__(256) void k_rownorm(const float* __restrict__ h,
                                                 unsigned short* __restrict__ xnF) {
    int t = threadIdx.x;
    int rl = t >> 4, j = t & 15;
    size_t row = (size_t)blockIdx.x * 16 + rl;
    const float* hr = h + row * FQ + j * 8;
    float v[8];
    #pragma unroll
    for (int e = 0; e < 8; ++e) v[e] = hr[e];
    float s = 0.f;
    #pragma unroll
    for (int e = 0; e < 8; ++e) s += v[e] * v[e];
    s += __shfl_xor(s, 1, 64);
    s += __shfl_xor(s, 2, 64);
    s += __shfl_xor(s, 4, 64);
    s += __shfl_xor(s, 8, 64);
    float inv = 1.0f / fmaxf(sqrtf(s), 1e-8f);
    us8 u;
    #pragma unroll
    for (int e = 0; e < 8; ++e) u[e] = f2bf(v[e] * inv);
    *(us8*)(xnF + (size_t)blockIdx.x * 2048 + j * 128 + rl * 8) = u;
}

// ---- Kernel 2 (r18): triangle S-tiles. Grid = 8 batches x 136 (I<=J) pairs. ----
__global__ __launch_bounds__(512) void k_adj(const unsigned short* __restrict__ xnF,
                                             unsigned char* __restrict__ adjF,
                                             float* __restrict__ dpart, float t) {
    __shared__ unsigned short As[16384];                 // 32 KB: I panel
    __shared__ union { unsigned short Bsh[16384];        // 32 KB: J panel ...
                       unsigned char  T2[128 * 132]; } ub;  // ... reused as bounce
    __shared__ float dsm[2][128];
    __shared__ float csm[2][128];

    int bid = blockIdx.x;
    int bb = bid & 7;                       // batch -> XCD locality
    int pr = bid >> 3;                      // pair index 0..135
    int I = 0;
    { int p = pr; while (p >= 16 - I) { p -= 16 - I; ++I; } pr = p; }
    int J = I + pr;

    int tid = threadIdx.x;
    int wid = tid >> 6, lane = tid & 63;
    int wr = wid >> 1, wc = wid & 1;        // 4 row-quarters x 2 col-halves
    int g = lane >> 4, c = lane & 15;

    const unsigned short* xb = xnF + (size_t)bb * NQ * FQ;
    int rowb = I * 128 + wr * 32;
    int colb = J * 128 + wc * 64;

    {   // stage panels (32 KB each, contiguous in xnF fragment layout)
        const unsigned short* srcA = xb + (size_t)(I * 8) * 2048;
        const unsigned short* srcB = xb + (size_t)(J * 8) * 2048;
        #pragma unroll
        for (int it = 0; it < 4; ++it) {
            __builtin_amdgcn_global_load_lds(
                (const __attribute__((address_space(1))) void*)(srcA + (size_t)(it * 512 + tid) * 8),
                (__attribute__((address_space(3))) void*)(As + (it * 512 + wid * 64) * 8),
                16, 0, 0);
            __builtin_amdgcn_global_load_lds(
                (const __attribute__((address_space(1))) void*)(srcB + (size_t)(it * 512 + tid) * 8),
                (__attribute__((address_space(3))) void*)(ub.Bsh + (it * 512 + wid * 64) * 8),
                16, 0, 0);
        }
    }
    __syncthreads();

    short8 a[2][4];
    #pragma unroll
    for (int mi = 0; mi < 2; ++mi)
        #pragma unroll
        for (int ks = 0; ks < 4; ++ks)
            a[mi][ks] = *(const short8*)(As + (wr * 2 + mi) * 2048 + (ks * 4 + g) * 128 + c * 8);

    f32x4 acc[2][4];
    #pragma unroll
    for (int mi = 0; mi < 2; ++mi)
        #pragma unroll
        for (int ni = 0; ni < 4; ++ni) acc[mi][ni] = (f32x4){0.f, 0.f, 0.f, 0.f};

    #pragma unroll
    for (int ni = 0; ni < 4; ++ni) {
        short8 b[4];
        #pragma unroll
        for (int ks = 0; ks < 4; ++ks)
            b[ks] = *(const short8*)(ub.Bsh + (wc * 4 + ni) * 2048 + (ks * 4 + g) * 128 + c * 8);
        #pragma unroll
        for (int mi = 0; mi < 2; ++mi)
            #pragma unroll
            for (int ks = 0; ks < 4; ++ks)
                acc[mi][ni] = __builtin_amdgcn_mfma_f32_16x16x32_bf16(a[mi][ks], b[ks], acc[mi][ni], 0, 0, 0);
    }

    __syncthreads();    // all Bsh reads done before T2 overlay writes

    unsigned char* adjb = adjF + (size_t)bb * NQ * NQ;
    float dl[2][4];
    float csl[4] = {0.f, 0.f, 0.f, 0.f};
    #pragma unroll
    for (int mi = 0; mi < 2; ++mi)
        #pragma unroll
        for (int r = 0; r < 4; ++r) dl[mi][r] = 0.f;

    #pragma unroll
    for (int mi = 0; mi < 2; ++mi)
        #pragma unroll
        for (int ni = 0; ni < 4; ++ni) {
            f32x4 v = acc[mi][ni];
            float x0 = (v[0] > t) ? v[0] : 0.0f;   // strict threshold in f32
            float x1 = (v[1] > t) ? v[1] : 0.0f;
            float x2 = (v[2] > t) ? v[2] : 0.0f;
            float x3 = (v[3] > t) ? v[3] : 0.0f;
            dl[mi][0] += x0; dl[mi][1] += x1; dl[mi][2] += x2; dl[mi][3] += x3;
            csl[ni] += x0 + x1 + x2 + x3;          // col partial (rows of this lane)
            unsigned int u = pk8lo(x0, x1, 0u);
            u = pk8hi(x2, x3, u);
            // store 1: mirror-transposed (n = col in J-range, m = row in I-range)
            *(unsigned int*)(adjb + (size_t)((colb >> 4) + ni) * NG
                                  + (size_t)((rowb >> 3) + mi * 2 + (g >> 1)) * 128
                                  + c * 8 + (g & 1) * 4) = u;
            // bounce for store 2 (skip on diagonal): T2[colL][rowL], stride 132
            if (I != J) {
                int colL = wc * 64 + ni * 16 + c;
                int rowL = wr * 32 + mi * 16 + g * 4;
                *(unsigned int*)(ub.T2 + colL * 132 + rowL) = u;
            }
        }

    // row sums -> dsm (reduce over c-lanes)
    #pragma unroll
    for (int mi = 0; mi < 2; ++mi)
        #pragma unroll
        for (int r = 0; r < 4; ++r) {
            float s = dl[mi][r];
            s += __shfl_xor(s, 1, 64);
            s += __shfl_xor(s, 2, 64);
            s += __shfl_xor(s, 4, 64);
            s += __shfl_xor(s, 8, 64);
            dl[mi][r] = s;
        }
    if (c == 0) {
        #pragma unroll
        for (int mi = 0; mi < 2; ++mi)
            #pragma unroll
            for (int r = 0; r < 4; ++r)
                dsm[wc][wr * 32 + mi * 16 + g * 4 + r] = dl[mi][r];
    }
    // col sums -> csm (reduce over g-lanes)
    if (I != J) {
        #pragma unroll
        for (int ni = 0; ni < 4; ++ni) {
            float s = csl[ni];
            s += __shfl_xor(s, 16, 64);
            s += __shfl_xor(s, 32, 64);
            csl[ni] = s;
        }
        if (lane < 16) {
            #pragma unroll
            for (int ni = 0; ni < 4; ++ni)
                csm[wr & 1][wc * 64 + ni * 16 + lane] = csl[ni];
        }
    }
    __syncthreads();
    if (I != J && (wr >= 2) && lane < 16) {
        #pragma unroll
        for (int ni = 0; ni < 4; ++ni)
            csm[wr & 1][wc * 64 + ni * 16 + lane] += csl[ni];
    }
    __syncthreads();

    // dpart writes
    if (tid < 128)
        dpart[((size_t)J * 8 + bb) * NQ + I * 128 + tid] = dsm[0][tid] + dsm[1][tid];
    if (I != J) {
        if (tid < 128)
            dpart[((size_t)I * 8 + bb) * NQ + J * 128 + tid] = csm[0][tid] + csm[1][tid];
        // store 2: direct orientation (n = row in I-range, m = col in J-range)
        int ng = wid;                 // 0..7 n-group within I-range
        int mg = lane >> 2;           // 0..15 m-group within J-range
        int part = lane & 3;          // n%16 quarter
        unsigned int w[8];
        #pragma unroll
        for (int ml = 0; ml < 8; ++ml)
            w[ml] = *(const unsigned int*)(ub.T2 + (mg * 8 + ml) * 132 + ng * 16 + part * 4);
        unsigned int o32[8];
        #pragma unroll
        for (int i = 0; i < 4; ++i)
            #pragma unroll
            for (int h = 0; h < 2; ++h)
                o32[i * 2 + h] = ((w[h * 4 + 0] >> (8 * i)) & 0xFFu)
                               | (((w[h * 4 + 1] >> (8 * i)) & 0xFFu) << 8)
                               | (((w[h * 4 + 2] >> (8 * i)) & 0xFFu) << 16)
                               | (((w[h * 4 + 3] >> (8 * i)) & 0xFFu) << 24);
        unsigned char* dst = adjb + (size_t)(I * 8 + ng) * NG + (size_t)(J * 16 + mg) * 128 + part * 32;
        *(u32x4*)dst        = (u32x4){o32[0], o32[1], o32[2], o32[3]};
        *(u32x4*)(dst + 16) = (u32x4){o32[4], o32[5], o32[6], o32[7]};
    }
}

// ---- Kernel 3a (iter 0): isq from dpart; hsF (fp8, xHSS) from f32 x ----
__global__ __launch_bounds__(256) void k_prep_f32(const float* __restrict__ h,
                                                  const float* __restrict__ dpart,
                                                  float* __restrict__ isq,
                                                  unsigned char* __restrict__ hsF) {
    __shared__ float tile[32][129];
    __shared__ float iv[32];
    int r0 = blockIdx.x * 32;
    int bb = r0 >> 11;
    int m0 = r0 & (NQ - 1);
    int tid = threadIdx.x;
    if (tid < 32) {
        float s = 0.f;
        #pragma unroll
        for (int j = 0; j < 16; ++j)
            s += dpart[((size_t)j * 8 + bb) * NQ + m0 + tid];
        float v = 1.0f / sqrtf(s);
        iv[tid] = v;
        isq[r0 + tid] = v;
    }
    #pragma unroll
    for (int it = 0; it < 16; ++it) {
        int idx = tid + it * 256;
        int mi = idx >> 7, f = idx & 127;
        tile[mi][f] = h[(size_t)(r0 + mi) * FQ + f];
    }
    __syncthreads();
    unsigned char* hb = hsF + (size_t)bb * NQ * FQ;
    #pragma unroll
    for (int it = 0; it < 2; ++it) {
        int p = tid + it * 256;
        int f = p & 127, mc = p >> 7;
        float sv[8];
        #pragma unroll
        for (int e = 0; e < 8; ++e)
            sv[e] = tile[mc * 8 + e][f] * iv[mc * 8 + e] * HSS;
        u32x2 u;
        u[0] = pk8hi(sv[2], sv[3], pk8lo(sv[0], sv[1], 0u));
        u[1] = pk8hi(sv[6], sv[7], pk8lo(sv[4], sv[5], 0u));
        *(u32x2*)(hb + (size_t)((m0 >> 3) + mc) * 1024 + f * 8) = u;
    }
}

// ---- Kernel 3b (iters 1,2): isq from dpart; hsF (fp8) from bf16 h ----
__global__ __launch_bounds__(256) void k_prep_bf16(const unsigned short* __restrict__ h,
                                                   const float* __restrict__ dpart,
                                                   float* __restrict__ isq,
                                                   unsigned char* __restrict__ hsF) {
    __shared__ float tile[32][129];
    __shared__ float iv[32];
    int r0 = blockIdx.x * 32;
    int bb = r0 >> 11;
    int m0 = r0 & (NQ - 1);
    int tid = threadIdx.x;
    if (tid < 32) {
        float s = 0.f;
        #pragma unroll
        for (int j = 0; j < 16; ++j)
            s += dpart[((size_t)j * 8 + bb) * NQ + m0 + tid];
        float v = 1.0f / sqrtf(s);
        iv[tid] = v;
        isq[r0 + tid] = v;
    }
    #pragma unroll
    for (int it = 0; it < 16; ++it) {
        int idx = tid + it * 256;
        int mi = idx >> 7, f = idx & 127;
        tile[mi][f] = bf2f(h[(size_t)(r0 + mi) * FQ + f]);
    }
    __syncthreads();
    unsigned char* hb = hsF + (size_t)bb * NQ * FQ;
    #pragma unroll
    for (int it = 0; it < 2; ++it) {
        int p = tid + it * 256;
        int f = p & 127, mc = p >> 7;
        float sv[8];
        #pragma unroll
        for (int e = 0; e < 8; ++e)
            sv[e] = tile[mc * 8 + e][f] * iv[mc * 8 + e] * HSS;
        u32x2 u;
        u[0] = pk8hi(sv[2], sv[3], pk8lo(sv[0], sv[1], 0u));
        u[1] = pk8hi(sv[6], sv[7], pk8lo(sv[4], sv[5], 0u));
        *(u32x2*)(hb + (size_t)((m0 >> 3) + mc) * 1024 + f * 8) = u;
    }
}

// ---- Kernel 4 (r19): h_out = isq*(adjF_fp8 @ hsF_fp8)/HSS + in-block row-norm.
//      32-row blocks, grid 512 = 2 blocks/CU; 8 waves = 2 rg (16 rows) x 4 kh (K=512). ----
template<bool LAST>
__global__ __launch_bounds__(512) void k_gemm3(const unsigned char* __restrict__ adjF,
                                               const unsigned char* __restrict__ hsF,
                                               const float* __restrict__ isq,
                                               unsigned short* __restrict__ hout,
                                               unsigned short* __restrict__ xnF) {
    __shared__ unsigned char Bs[32768];        // 4 kh regions x 8 KB phase slice
    __shared__ float red[32][128];             // 16 KB f32 partial-sum buffer

    int bid = blockIdx.x;
    int lb = (bid & 7) * 64 + (bid >> 3);      // XCD swizzle (grid 512)
    int bb = lb >> 6;
    int rt = lb & 63;
    int row0g = rt * 32;
    int tid = threadIdx.x;
    int wid = tid >> 6, lane = tid & 63;
    int g = lane >> 4, c = lane & 15;
    int rg = wid >> 2, kh = wid & 3;
    int wrow = row0g + rg * 16;                // this wave's single n-group

    const unsigned char* adjr = adjF + (size_t)bb * NQ * NQ + (size_t)(wrow >> 4) * NG;
    const unsigned char* hb   = hsF + (size_t)bb * NQ * FQ;

    f32x4 acc[8];
    #pragma unroll
    for (int i = 0; i < 8; ++i) acc[i] = (f32x4){0.f, 0.f, 0.f, 0.f};

    int khr = wid >> 1;            // staging region this wave fills (2 waves/region)
    int wlo = wid & 1;

    for (int ph = 0; ph < 8; ++ph) {
        __syncthreads();           // previous phase's readers done
        {
            const unsigned char* src = hb + (size_t)(khr * 64 + ph * 8) * 1024 + wlo * 1024;
            unsigned char* dst = Bs + khr * 8192 + wlo * 1024;
            #pragma unroll
            for (int it = 0; it < 4; ++it) {
                __builtin_amdgcn_global_load_lds(
                    (const __attribute__((address_space(1))) void*)(src + it * 2048 + lane * 16),
                    (__attribute__((address_space(3))) void*)(dst + it * 2048),
                    16, 0, 0);
            }
        }
        __syncthreads();           // drains vmcnt
        #pragma unroll
        for (int kk2 = 0; kk2 < 2; ++kk2) {
            int mstep = kh * 16 + ph * 2 + kk2;     // global 32-elem K step
            long a0 = *(const long*)(adjr + (size_t)(mstep * 4 + g) * 128 + c * 8);
            #pragma unroll
            for (int ct = 0; ct < 8; ++ct) {
                long bfr = *(const long*)(Bs + kh * 8192 + kk2 * 4096 + g * 1024 + (ct * 16 + c) * 8);
                acc[ct] = __builtin_amdgcn_mfma_f32_16x16x32_fp8_fp8(a0, bfr, acc[ct], 0, 0, 0);
            }
        }
    }

    // cross-kh reduction into red (barrier-ordered, deterministic)
    __syncthreads();
    #pragma unroll
    for (int s = 0; s < 4; ++s) {
        if (kh == s) {
            #pragma unroll
            for (int ct = 0; ct < 8; ++ct)
                #pragma unroll
                for (int r = 0; r < 4; ++r) {
                    int rl = rg * 16 + g * 4 + r;
                    if (s == 0) red[rl][ct * 16 + c] = acc[ct][r];
                    else        red[rl][ct * 16 + c] += acc[ct][r];
                }
        }
        __syncthreads();
    }

    // final pass: scale, row-norm, write h bf16 (+ xnF fragments unless LAST)
    int rl = tid >> 4;             // 0..31
    int j  = tid & 15;             // 16 f-chunks of 8
    int n  = row0g + rl;
    float scale = isq[(size_t)bb * NQ + n] * (1.0f / HSS);
    float v[8];
    float s = 0.f;
    #pragma unroll
    for (int e = 0; e < 8; ++e) {
        float x = red[rl][j * 8 + e] * scale;
        v[e] = x;
        s += x * x;
    }
    s += __shfl_xor(s, 1, 64);
    s += __shfl_xor(s, 2, 64);
    s += __shfl_xor(s, 4, 64);
    s += __shfl_xor(s, 8, 64);
    float inv = 1.0f / fmaxf(sqrtf(s), 1e-8f);

    us8 h0;
    #pragma unroll
    for (int e = 0; e < 8; ++e) h0[e] = f2bf(v[e]);
    *(us8*)(hout + ((size_t)bb * NQ + n) * FQ + j * 8) = h0;

    if constexpr (!LAST) {
        us8 u0;
        #pragma unroll
        for (int e = 0; e < 8; ++e) u0[e] = f2bf(v[e] * inv);
        unsigned short* xd = xnF + (size_t)bb * NQ * FQ + (size_t)(n >> 4) * 2048
                                 + j * 128 + (n & 15) * 8;
        *(us8*)xd = u0;
    }
}

// ---- Kernel 5: out = (h3(bf16) + x) @ W ----
__global__ __launch_bounds__(256) void k_out(const unsigned short* __restrict__ h3,
                                             const float* __restrict__ x,
                                             const float* __restrict__ W,
                                             float* __restrict__ out) {
    __shared__ float hx[8][128];
    int r0 = blockIdx.x * 8;
    int tid = threadIdx.x;
    #pragma unroll
    for (int it = 0; it < 4; ++it) {
        int idx = tid + it * 256;
        int ri = idx >> 7, f = idx & 127;
        size_t gi = (size_t)(r0 + ri) * FQ + f;
        hx[ri][f] = bf2f(h3[gi]) + x[gi];
    }
    __syncthreads();
    int o = tid & 127, half = tid >> 7;
    float acc[4] = {0.f, 0.f, 0.f, 0.f};
    for (int f = 0; f < 128; ++f) {
        float wv = W[f * 128 + o];
        #pragma unroll
        for (int j = 0; j < 4; ++j)
            acc[j] += hx[half * 4 + j][f] * wv;
    }
    #pragma unroll
    for (int j = 0; j < 4; ++j)
        out[(size_t)(r0 + half * 4 + j) * FQ + o] = acc[j];
}

extern "C" void kernel_launch(void* const* d_in, const int* in_sizes, int n_in,
                              void* d_out, int out_size, void* d_ws, size_t ws_size,
                              hipStream_t stream) {
    const float* x = (const float*)d_in[0];
    const float* W = (const float*)d_in[1];
    float* out = (float*)d_out;
    char* ws = (char*)d_ws;

    const size_t CS   = (size_t)BQ * NQ * FQ;
    const size_t oADJ = 0;
    const size_t oXN  = oADJ + (size_t)BQ * NQ * NQ;          // 32 MiB fp8 adj
    const size_t oHST = oXN  + CS * 2;                        // +4 MiB bf16 xn
    const size_t oD   = oHST + CS;                            // +2 MiB fp8 hs
    const size_t oISQ = oD   + (size_t)16 * BQ * NQ * 4;      // +1 MiB
    const size_t oHA  = oISQ + (size_t)BQ * NQ * 4;           // +64 KiB
    const size_t oHB  = oHA  + CS * 2;                        // +4 MiB bf16 hA
    const size_t need = oHB  + CS * 2;                        // +4 MiB bf16 hB
    if (ws_size < need) return;   // diagnostic: output stays poisoned

    unsigned char*  adjF = (unsigned char*)(ws + oADJ);
    unsigned short* xnF  = (unsigned short*)(ws + oXN);
    unsigned char*  hsF  = (unsigned char*)(ws + oHST);
    float* dpart = (float*)(ws + oD);
    float* isq   = (float*)(ws + oISQ);
    unsigned short* hA = (unsigned short*)(ws + oHA);
    unsigned short* hB = (unsigned short*)(ws + oHB);

    const float ts[3] = {0.05f, 0.1f, 0.15f};

    // iter 0
    k_rownorm<<<BQ * NQ / 16, 256, 0, stream>>>(x, xnF);
    k_adj<<<BQ * 136, 512, 0, stream>>>(xnF, adjF, dpart, ts[0]);
    k_prep_f32<<<BQ * NQ / 32, 256, 0, stream>>>(x, dpart, isq, hsF);
    k_gemm3<false><<<BQ * 64, 512, 0, stream>>>(adjF, hsF, isq, hA, xnF);
    // iter 1
    k_adj<<<BQ * 136, 512, 0, stream>>>(xnF, adjF, dpart, ts[1]);
    k_prep_bf16<<<BQ * NQ / 32, 256, 0, stream>>>(hA, dpart, isq, hsF);
    k_gemm3<false><<<BQ * 64, 512, 0, stream>>>(adjF, hsF, isq, hB, xnF);
    // iter 2
    k_adj<<<BQ * 136, 512, 0, stream>>>(xnF, adjF, dpart, ts[2]);
    k_prep_bf16<<<BQ * NQ / 32, 256, 0, stream>>>(hB, dpart, isq, hsF);
    k_gemm3<true><<<BQ * 64, 512, 0, stream>>>(adjF, hsF, isq, hA, xnF);

    k_out<<<BQ * NQ / 8, 256, 0, stream>>>(hA, x, W, out);
}